// Round 1
// baseline (5720.530 us; speedup 1.0000x reference)
//
#include <hip/hip_runtime.h>
#include <float.h>

// Problem constants (from setup_inputs)
#define NROWS 65536      // B*H*W*D = 16*16*16*16
#define CDIM  256        // channels
#define KS    1024       // structure codes
#define KY    512        // style codes
#define SPB   4096       // spatial elements per batch (H*W*D)

// Workspace layout (float indices)
#define OFF_S_COUNTS 0                    // 1024
#define OFF_Y_COUNTS 1024                 // 512
#define OFF_S_DW     1536                 // 262144
#define OFF_Y_DW     263680               // 131072
#define OFF_DIS      394752               // 1
#define ZERO_FLOATS  394753
#define OFF_S_NORM   394753               // 1024
#define OFF_Y_NORM   395777               // 512
#define OFF_S_SCALE  396289               // 1024
#define OFF_Y_SCALE  397313               // 512
#define OFF_S_EMB    397825               // 262144
#define OFF_Y_EMB    659969               // 131072
#define OFF_S_IDX    791041               // 65536 (int)
#define OFF_Y_IDX    856577               // 65536 (int)

// Output layout (float indices into d_out)
#define OFF_OUT_ZQ   0
#define OFF_OUT_DIS  16777216
#define OFF_OUT_SIDX 16777217
#define OFF_OUT_YIDX 16842753

// ---------------------------------------------------------------------------
// |e_k|^2 for both codebooks. grid = KS+KY blocks of 64 threads (1 wave/row).
__global__ void norms_kernel(const float* __restrict__ Es, const float* __restrict__ Ey,
                             float* __restrict__ sn, float* __restrict__ yn) {
    int row = blockIdx.x;
    const float* E; float* out; int r;
    if (row < KS) { E = Es; out = sn; r = row; }
    else          { E = Ey; out = yn; r = row - KS; }
    int lane = threadIdx.x;
    float v = 0.f;
#pragma unroll
    for (int j = 0; j < 4; ++j) {
        float e = E[r * CDIM + lane + j * 64];
        v += e * e;
    }
#pragma unroll
    for (int off = 32; off > 0; off >>= 1) v += __shfl_down(v, off);
    if (lane == 0) out[r] = v;
}

// ---------------------------------------------------------------------------
// Distance matmul + argmin + EMA scatter.
// Tiles: 64 rows x 64 codes per block, 4x4 per thread, c-chunks of 16.
// z layout: z[(b*CDIM + c)*SPB + s], row n = b*SPB + s  (z_flat[n][c])
__global__ void dist_kernel(const float* __restrict__ z, const float* __restrict__ E,
                            const float* __restrict__ enorm2, int K,
                            float* __restrict__ idx_f_out, int* __restrict__ idx_i_out,
                            float* __restrict__ counts, float* __restrict__ dw) {
    __shared__ float Zs[16][68];
    __shared__ float Es_[16][68];
    __shared__ float redv[64 * 16];
    __shared__ int   redi[64 * 16];
    __shared__ int   bestk[64];

    const int tid = threadIdx.x;
    const int n0  = blockIdx.x * 64;
    const int b   = n0 >> 12;      // n0 / 4096 (tile never crosses batch: 64 | 4096)
    const int s0  = n0 & 4095;
    const float* zb = z + (size_t)b * CDIM * SPB + s0;
    const int ty = tid >> 4;       // 0..15 -> row group
    const int tx = tid & 15;       // 0..15 -> k group

    float minv[4]; int mini[4];
#pragma unroll
    for (int i = 0; i < 4; ++i) { minv[i] = FLT_MAX; mini[i] = 0; }

    for (int kt = 0; kt < K; kt += 64) {
        float acc[4][4];
#pragma unroll
        for (int i = 0; i < 4; ++i)
#pragma unroll
            for (int j = 0; j < 4; ++j) acc[i][j] = 0.f;

        for (int c0 = 0; c0 < CDIM; c0 += 16) {
            __syncthreads();
#pragma unroll
            for (int i = 0; i < 4; ++i) {
                int l  = i * 256 + tid;
                int cc = l >> 6, r = l & 63;          // Z chunk: 16c x 64r
                Zs[cc][r] = zb[(size_t)(c0 + cc) * SPB + r];
                int kk = l >> 4, c2 = l & 15;         // E chunk: 64k x 16c (transposed store)
                Es_[c2][kk] = E[(size_t)(kt + kk) * CDIM + c0 + c2];
            }
            __syncthreads();
#pragma unroll
            for (int cc = 0; cc < 16; ++cc) {
                const float4 zr = *reinterpret_cast<const float4*>(&Zs[cc][ty * 4]);
                const float4 ek = *reinterpret_cast<const float4*>(&Es_[cc][tx * 4]);
                float a4[4] = { zr.x, zr.y, zr.z, zr.w };
                float b4[4] = { ek.x, ek.y, ek.z, ek.w };
#pragma unroll
                for (int i = 0; i < 4; ++i)
#pragma unroll
                    for (int j = 0; j < 4; ++j)
                        acc[i][j] = fmaf(a4[i], b4[j], acc[i][j]);
            }
        }
        // fold this k-tile into the running argmin (k ascending within thread)
#pragma unroll
        for (int j = 0; j < 4; ++j) {
            int k = kt + tx * 4 + j;
            float en = enorm2[k];
#pragma unroll
            for (int i = 0; i < 4; ++i) {
                float s = en - 2.f * acc[i][j];
                if (s < minv[i]) { minv[i] = s; mini[i] = k; }
            }
        }
    }

#pragma unroll
    for (int i = 0; i < 4; ++i) {
        int r = ty * 4 + i;
        redv[r * 16 + tx] = minv[i];
        redi[r * 16 + tx] = mini[i];
    }
    __syncthreads();
    if (tid < 64) {
        float bv = redv[tid * 16]; int bi = redi[tid * 16];
        for (int t = 1; t < 16; ++t) {
            float v = redv[tid * 16 + t]; int id = redi[tid * 16 + t];
            // first-occurrence min (jnp.argmin semantics): tx ascending == k ascending
            if (v < bv || (v == bv && id < bi)) { bv = v; bi = id; }
        }
        int n = n0 + tid;
        idx_f_out[n] = (float)bi;
        idx_i_out[n] = bi;
        atomicAdd(&counts[bi], 1.0f);
        bestk[tid] = bi;
    }
    __syncthreads();
    // dw scatter: re-read z coalesced (c-major), atomic add into dw[k][c]
    for (int i = 0; i < 64; ++i) {
        int l = i * 256 + tid;     // 16384 = 64 rows * 256 channels
        int r = l & 63;
        int c = l >> 6;
        float v = zb[(size_t)c * SPB + r];
        atomicAdd(&dw[(size_t)bestk[r] * CDIM + c], v);
    }
}

// ---------------------------------------------------------------------------
// Per-codebook balance: new_cs -> n -> scale[k] = 1/bal[k]. One block, K threads.
__global__ void balance_kernel(const float* __restrict__ cs, const float* __restrict__ counts,
                               float* __restrict__ scale, int K) {
    __shared__ float sd[1024];
    int t = threadIdx.x;
    float ncs = cs[t] * 0.99f + 0.01f * counts[t];
    sd[t] = ncs;
    __syncthreads();
    for (int s = blockDim.x / 2; s > 0; s >>= 1) {
        if (t < s) sd[t] += sd[t + s];
        __syncthreads();
    }
    float n = sd[0];
    float bal = (ncs + 1e-5f) / (n + (float)K * 1e-5f) * n;
    scale[t] = 1.0f / bal;
}

// ---------------------------------------------------------------------------
// new_emb[k][c] = (avg*0.99 + 0.01*dw) * scale[k].  grid = K blocks of 256.
__global__ void embnew_kernel(const float* __restrict__ avg, const float* __restrict__ dw,
                              const float* __restrict__ scale, float* __restrict__ emb) {
    int i = blockIdx.x * 256 + threadIdx.x;
    int k = i >> 8;
    emb[i] = (avg[i] * 0.99f + 0.01f * dw[i]) * scale[k];
}

// ---------------------------------------------------------------------------
// Gather z_q = 0.5*(s_enc + y_enc), plus dis partial sums.
// One block per (b,h,w) group: 16 d-positions x 256 channels.
__global__ void gather_kernel(const float* __restrict__ Se, const float* __restrict__ Ye,
                              const int* __restrict__ sidx, const int* __restrict__ yidx,
                              float* __restrict__ zq, float* __restrict__ disacc) {
    __shared__ float qb[256 * 17];
    __shared__ int   si[16], yi[16];
    __shared__ float red[256];
    const int g  = blockIdx.x;        // 0..4095 = b*256 + hw
    const int b  = g >> 8;
    const int hw = g & 255;
    const int t  = threadIdx.x;       // channel c
    if (t < 16) {
        int n = b * SPB + hw * 16 + t;
        si[t] = sidx[n];
        yi[t] = yidx[n];
    }
    __syncthreads();
    float ns = 0.f, ny = 0.f, dot = 0.f;
#pragma unroll
    for (int d = 0; d < 16; ++d) {
        float s = Se[(size_t)si[d] * CDIM + t];
        float y = Ye[(size_t)yi[d] * CDIM + t];
        ns  = fmaf(s, s, ns);
        ny  = fmaf(y, y, ny);
        dot = fmaf(s, y, dot);
        qb[t * 17 + d] = 0.5f * (s + y);
    }
    float den = fmaxf(sqrtf(ns), 1e-12f) * fmaxf(sqrtf(ny), 1e-12f);
    float val = dot / den;
    red[t] = val * val;
    __syncthreads();
    for (int s = 128; s > 0; s >>= 1) {
        if (t < s) red[t] += red[t + s];
        __syncthreads();
    }
    if (t == 0) atomicAdd(disacc, red[0]);
    // write z_q: out[(b*CDIM + c)*SPB + hw*16 + d]; 16 consecutive d per c
    float* zg = zq + (size_t)b * CDIM * SPB + hw * 16;
#pragma unroll
    for (int j = 0; j < 16; ++j) {
        int e = j * 256 + t;
        int c = e >> 4, d = e & 15;
        zg[(size_t)c * SPB + d] = qb[c * 17 + d];
    }
}

__global__ void fin_kernel(const float* __restrict__ disacc, float* __restrict__ out_dis) {
    *out_dis = *disacc * (1.0f / 1048576.0f);   // mean over B*C*H*W
}

// ---------------------------------------------------------------------------
extern "C" void kernel_launch(void* const* d_in, const int* in_sizes, int n_in,
                              void* d_out, int out_size, void* d_ws, size_t ws_size,
                              hipStream_t stream) {
    const float* z     = (const float*)d_in[0];
    const float* Es    = (const float*)d_in[1];
    const float* Ey    = (const float*)d_in[2];
    const float* s_cs  = (const float*)d_in[3];
    const float* y_cs  = (const float*)d_in[4];
    const float* s_avg = (const float*)d_in[5];
    const float* y_avg = (const float*)d_in[6];
    float* out = (float*)d_out;
    float* ws  = (float*)d_ws;

    // zero accumulators (counts, dw, dis) — required every call (no re-poison)
    hipMemsetAsync(ws, 0, (size_t)ZERO_FLOATS * sizeof(float), stream);

    norms_kernel<<<KS + KY, 64, 0, stream>>>(Es, Ey, ws + OFF_S_NORM, ws + OFF_Y_NORM);

    dist_kernel<<<NROWS / 64, 256, 0, stream>>>(
        z, Es, ws + OFF_S_NORM, KS,
        out + OFF_OUT_SIDX, (int*)(ws + OFF_S_IDX),
        ws + OFF_S_COUNTS, ws + OFF_S_DW);
    dist_kernel<<<NROWS / 64, 256, 0, stream>>>(
        z, Ey, ws + OFF_Y_NORM, KY,
        out + OFF_OUT_YIDX, (int*)(ws + OFF_Y_IDX),
        ws + OFF_Y_COUNTS, ws + OFF_Y_DW);

    balance_kernel<<<1, KS, 0, stream>>>(s_cs, ws + OFF_S_COUNTS, ws + OFF_S_SCALE, KS);
    balance_kernel<<<1, KY, 0, stream>>>(y_cs, ws + OFF_Y_COUNTS, ws + OFF_Y_SCALE, KY);

    embnew_kernel<<<KS, 256, 0, stream>>>(s_avg, ws + OFF_S_DW, ws + OFF_S_SCALE, ws + OFF_S_EMB);
    embnew_kernel<<<KY, 256, 0, stream>>>(y_avg, ws + OFF_Y_DW, ws + OFF_Y_SCALE, ws + OFF_Y_EMB);

    gather_kernel<<<4096, 256, 0, stream>>>(
        ws + OFF_S_EMB, ws + OFF_Y_EMB,
        (int*)(ws + OFF_S_IDX), (int*)(ws + OFF_Y_IDX),
        out + OFF_OUT_ZQ, ws + OFF_DIS);

    fin_kernel<<<1, 1, 0, stream>>>(ws + OFF_DIS, out + OFF_OUT_DIS);
}

// Round 2
// 1392.661 us; speedup vs baseline: 4.1076x; 4.1076x over previous
//
#include <hip/hip_runtime.h>
#include <float.h>

// Problem constants
#define NROWS 65536      // B*H*W*D
#define CDIM  256
#define KS    1024
#define KY    512
#define KTOT  1536
#define SPB   4096       // H*W*D per batch
#define TAU   0.05f
#define RESCUE_CAP 8192

// ---- workspace byte offsets ----
#define WB_CNT_S       0         // 1024 int
#define WB_CNT_Y       4096      // 512 int
#define WB_RESCUE_CNT  6144      // 1 int
#define WB_DISACC      6148      // 1 float
#define WB_ZERO_BYTES  6152      // memset [0, 6152)
#define WB_EIMG        6208      // 24 chunks * 65536 B (ushort bf16 image)
#define WB_EN2         1579072   // 1536 f32
#define WB_IDXS_I      1585216   // 65536 int
#define WB_IDXY_I      1847360   // 65536 int
#define WB_RESCUE_LIST 2109504   // 8192 int
#define WB_BASE_S      2142272   // 1024 int
#define WB_BASE_Y      2146368   // 512 int
#define WB_CUR_S       2148416   // 1024 int
#define WB_CUR_Y       2152512   // 512 int
#define WB_SCALE_S     2154560   // 1024 f32
#define WB_SCALE_Y     2158656   // 512 f32
#define WB_PERM_S      2160704   // 65536 int
#define WB_PERM_Y      2422848   // 65536 int
#define WB_DW_S        2684992   // 1024*256 f32
#define WB_DW_Y        3733568   // 512*256 f32
#define WB_EMB_S       4257856   // 1024*256 f32
#define WB_EMB_Y       5306432   // 512*256 f32

// ---- output float offsets ----
#define OFF_OUT_ZQ   0
#define OFF_OUT_DIS  16777216
#define OFF_OUT_SIDX 16777217
#define OFF_OUT_YIDX 16842753

typedef __attribute__((ext_vector_type(8)))  __bf16 bf16x8;
typedef __attribute__((ext_vector_type(16))) float  f32x16;
typedef __attribute__((ext_vector_type(8)))  unsigned short ushort8;

__device__ __forceinline__ unsigned int bf16rne(float f) {
    unsigned int u = __float_as_uint(f);
    return (u + 0x7fffu + ((u >> 16) & 1u)) >> 16;
}

// ---------------------------------------------------------------------------
// Codebook prep: combined (structure ++ style) -> bf16 hi/lo fragment-linear
// LDS images (chunk = 64 codes = 64KB) + |e|^2 fp32. One wave per code row.
__global__ void prep_e(const float* __restrict__ Es, const float* __restrict__ Ey,
                       unsigned short* __restrict__ eimg, float* __restrict__ en2) {
    int k = blockIdx.x;            // 0..1535 global code
    int lane = threadIdx.x;        // 64
    const float* E = (k < KS) ? (Es + (size_t)k * CDIM) : (Ey + (size_t)(k - KS) * CDIM);
    float4 v = *(const float4*)(E + lane * 4);
    float nrm = v.x * v.x + v.y * v.y + v.z * v.z + v.w * v.w;
#pragma unroll
    for (int off = 32; off > 0; off >>= 1) nrm += __shfl_down(nrm, off);
    if (lane == 0) en2[k] = nrm;

    unsigned int h0 = bf16rne(v.x), h1 = bf16rne(v.y), h2 = bf16rne(v.z), h3 = bf16rne(v.w);
    float r0 = v.x - __uint_as_float(h0 << 16);
    float r1 = v.y - __uint_as_float(h1 << 16);
    float r2 = v.z - __uint_as_float(h2 << 16);
    float r3 = v.w - __uint_as_float(h3 << 16);
    unsigned int l0 = bf16rne(r0), l1 = bf16rne(r1), l2 = bf16rne(r2), l3 = bf16rne(r3);
    uint2 hp = make_uint2(h0 | (h1 << 16), h2 | (h3 << 16));
    uint2 lp = make_uint2(l0 | (l1 << 16), l2 | (l3 << 16));

    int t = k >> 6, kk = k & 63, ktile = kk >> 5, kin = kk & 31;
    int cc = lane >> 2, g = (lane & 3) >> 1, j0 = (lane & 1) * 4;
    // fragment order: (ktile, cc, part) blocks of 1024B; lane slot = kin + 32*g
    size_t base = (size_t)t * 32768 + (size_t)(((ktile * 16 + cc) * 2 + 0) * 512)
                + (size_t)((kin + 32 * g) * 8 + j0);          // ushort units
    *(uint2*)(eimg + base)        = hp;
    *(uint2*)(eimg + base + 512)  = lp;                        // lo part block
}

// ---------------------------------------------------------------------------
// Transpose z -> zf[n][c] fp32 (written into d_out zq region as scratch).
__global__ void prep_z(const float* __restrict__ z, float* __restrict__ zf) {
    __shared__ float Zs[32][257];
    int blk = blockIdx.x;          // 2048
    int n0 = blk * 32, b = n0 >> 12, s0 = n0 & 4095;
    int t = threadIdx.x;
    const float* zb = z + (size_t)b * CDIM * SPB + s0;
#pragma unroll
    for (int i = 0; i < 32; ++i) {
        int l = i * 256 + t;       // c*32 + s
        int c = l >> 5, s = l & 31;
        Zs[s][c] = zb[(size_t)c * SPB + s];
    }
    __syncthreads();
#pragma unroll
    for (int j = 0; j < 8; ++j) {
        int gid = j * 256 + t;     // nl*64 + fg
        int nl = gid >> 6, fg = gid & 63;
        float4 v = *(const float4*)(&Zs[nl][fg * 4]);
        *(float4*)(&zf[(size_t)(n0 + nl) * 256 + fg * 4]) = v;
    }
}

// ---------------------------------------------------------------------------
// MFMA assign: per block 128 rows (4 waves x 32), loop both codebooks.
__launch_bounds__(256, 2)
__global__ void assign_kernel(const float* __restrict__ z, const unsigned short* __restrict__ eimg,
                              const float* __restrict__ en2,
                              float* __restrict__ sidx_f, float* __restrict__ yidx_f,
                              int* __restrict__ sidx_i, int* __restrict__ yidx_i,
                              int* __restrict__ rescue_cnt, int* __restrict__ rescue_list) {
    __shared__ unsigned short sh[32768];   // 64KB chunk image
    const int tid = threadIdx.x, wave = tid >> 6, lane = tid & 63;
    const int n0 = blockIdx.x * 128;
    const int b = n0 >> 12;
    const int myrow_s = (n0 & 4095) + wave * 32 + (lane & 31);
    const float* zb = z + (size_t)b * CDIM * SPB;
    const int g8 = (lane >> 5) * 8;

    // A fragments (register-resident): 16 c-chunks x {hi,lo}
    bf16x8 Ah[16], Al[16];
#pragma unroll
    for (int cc = 0; cc < 16; ++cc) {
        ushort8 uh, ul;
#pragma unroll
        for (int j = 0; j < 8; ++j) {
            float f = zb[(size_t)(cc * 16 + g8 + j) * SPB + myrow_s];
            unsigned int h = bf16rne(f);
            float r = f - __uint_as_float(h << 16);
            uh[j] = (unsigned short)h;
            ul[j] = (unsigned short)bf16rne(r);
        }
        Ah[cc] = __builtin_bit_cast(bf16x8, uh);
        Al[cc] = __builtin_bit_cast(bf16x8, ul);
    }

    for (int book = 0; book < 2; ++book) {
        const int t0 = book ? 16 : 0, t1 = book ? 24 : 16, kbase = book ? KS : 0;
        float minv[16], minv2[16]; int mini[16];
#pragma unroll
        for (int i = 0; i < 16; ++i) { minv[i] = FLT_MAX; minv2[i] = FLT_MAX; mini[i] = 0; }

        for (int t = t0; t < t1; ++t) {
            // stage 64KB chunk (reg-staged, coalesced)
            {
                const float4* gs = (const float4*)((const char*)eimg + (size_t)t * 65536) + tid;
                float4* ls = (float4*)((char*)sh) + tid;
#pragma unroll
                for (int ib = 0; ib < 4; ++ib) {
                    float4 tmp0 = gs[(ib * 4 + 0) * 256];
                    float4 tmp1 = gs[(ib * 4 + 1) * 256];
                    float4 tmp2 = gs[(ib * 4 + 2) * 256];
                    float4 tmp3 = gs[(ib * 4 + 3) * 256];
                    ls[(ib * 4 + 0) * 256] = tmp0;
                    ls[(ib * 4 + 1) * 256] = tmp1;
                    ls[(ib * 4 + 2) * 256] = tmp2;
                    ls[(ib * 4 + 3) * 256] = tmp3;
                }
            }
            __syncthreads();

            const int kb = t * 64 + (lane & 31);
            const float en0 = en2[kb], en1 = en2[kb + 32];
            f32x16 acc0 = {}, acc1 = {};
            const char* shb = (const char*)sh + lane * 16;
#pragma unroll
            for (int cc = 0; cc < 16; ++cc) {
                bf16x8 bh0 = *(const bf16x8*)(shb + (size_t)((cc * 2 + 0) * 1024));
                bf16x8 bl0 = *(const bf16x8*)(shb + (size_t)((cc * 2 + 1) * 1024));
                bf16x8 bh1 = *(const bf16x8*)(shb + (size_t)(((16 + cc) * 2 + 0) * 1024));
                bf16x8 bl1 = *(const bf16x8*)(shb + (size_t)(((16 + cc) * 2 + 1) * 1024));
                acc0 = __builtin_amdgcn_mfma_f32_32x32x16_bf16(Ah[cc], bh0, acc0, 0, 0, 0);
                acc1 = __builtin_amdgcn_mfma_f32_32x32x16_bf16(Ah[cc], bh1, acc1, 0, 0, 0);
                acc0 = __builtin_amdgcn_mfma_f32_32x32x16_bf16(Ah[cc], bl0, acc0, 0, 0, 0);
                acc1 = __builtin_amdgcn_mfma_f32_32x32x16_bf16(Ah[cc], bl1, acc1, 0, 0, 0);
                acc0 = __builtin_amdgcn_mfma_f32_32x32x16_bf16(Al[cc], bh0, acc0, 0, 0, 0);
                acc1 = __builtin_amdgcn_mfma_f32_32x32x16_bf16(Al[cc], bh1, acc1, 0, 0, 0);
                acc0 = __builtin_amdgcn_mfma_f32_32x32x16_bf16(Al[cc], bl0, acc0, 0, 0, 0);
                acc1 = __builtin_amdgcn_mfma_f32_32x32x16_bf16(Al[cc], bl1, acc1, 0, 0, 0);
            }
#pragma unroll
            for (int i = 0; i < 16; ++i) {
                float d0 = fmaf(-2.f, acc0[i], en0);
                if (d0 < minv[i]) { minv2[i] = minv[i]; minv[i] = d0; mini[i] = kb; }
                else minv2[i] = fminf(minv2[i], d0);
                float d1 = fmaf(-2.f, acc1[i], en1);
                if (d1 < minv[i]) { minv2[i] = minv[i]; minv[i] = d1; mini[i] = kb + 32; }
                else minv2[i] = fminf(minv2[i], d1);
            }
            __syncthreads();
        }

        // cross-lane argmin over the 32 lanes sharing each output row
        float* idx_f = book ? yidx_f : sidx_f;
        int*   idx_i = book ? yidx_i : sidx_i;
#pragma unroll
        for (int i = 0; i < 16; ++i) {
            float v1 = minv[i], v2 = minv2[i]; int k1 = mini[i];
#pragma unroll
            for (int m = 16; m >= 1; m >>= 1) {
                float ov1 = __shfl_xor(v1, m);
                int   ok1 = __shfl_xor(k1, m);
                float ov2 = __shfl_xor(v2, m);
                if (ov1 < v1 || (ov1 == v1 && ok1 < k1)) { v2 = fminf(ov2, v1); v1 = ov1; k1 = ok1; }
                else v2 = fminf(v2, fminf(ov1, ov2));
            }
            if ((lane & 31) == 0) {
                int r = (i & 3) + 8 * (i >> 2) + 4 * (lane >> 5);
                int n = n0 + wave * 32 + r;
                int kw = k1 - kbase;
                idx_f[n] = (float)kw;
                idx_i[n] = kw;
                if (v2 - v1 < TAU) {
                    int p = atomicAdd(rescue_cnt, 1);
                    if (p < RESCUE_CAP) rescue_list[p] = n | (book << 24);
                }
            }
        }
    }
}

// ---------------------------------------------------------------------------
// Exact-fp32 re-argmin for near-tie rows.
__global__ void rescue_kernel(const float* __restrict__ z, const float* __restrict__ Es,
                              const float* __restrict__ Ey, const float* __restrict__ en2,
                              const int* __restrict__ rescue_cnt, const int* __restrict__ rescue_list,
                              float* __restrict__ sidx_f, float* __restrict__ yidx_f,
                              int* __restrict__ sidx_i, int* __restrict__ yidx_i) {
    __shared__ float zrow[256];
    __shared__ float rv[256];
    __shared__ int   rk[256];
    int cnt = *rescue_cnt; if (cnt > RESCUE_CAP) cnt = RESCUE_CAP;
    int t = threadIdx.x;
    for (int e = blockIdx.x; e < cnt; e += gridDim.x) {
        int ent = rescue_list[e];
        int n = ent & 0x00FFFFFF, book = ent >> 24;
        int b = n >> 12, s = n & 4095;
        __syncthreads();
        zrow[t] = z[((size_t)b * CDIM + t) * SPB + s];
        __syncthreads();
        int K = book ? KY : KS, kb = book ? KS : 0;
        const float* E = book ? Ey : Es;
        float bv = FLT_MAX; int bk = 0;
        for (int k = t; k < K; k += 256) {
            const float* er = E + (size_t)k * CDIM;
            float dot = 0.f;
            for (int c = 0; c < 256; ++c) dot = fmaf(zrow[c], er[c], dot);
            float d = en2[kb + k] - 2.f * dot;
            if (d < bv) { bv = d; bk = k; }
        }
        rv[t] = bv; rk[t] = bk;
        __syncthreads();
        for (int s2 = 128; s2 > 0; s2 >>= 1) {
            if (t < s2) {
                float ov = rv[t + s2]; int ok = rk[t + s2];
                if (ov < rv[t] || (ov == rv[t] && ok < rk[t])) { rv[t] = ov; rk[t] = ok; }
            }
            __syncthreads();
        }
        if (t == 0) {
            if (book) { yidx_f[n] = (float)rk[0]; yidx_i[n] = rk[0]; }
            else      { sidx_f[n] = (float)rk[0]; sidx_i[n] = rk[0]; }
        }
    }
}

// ---------------------------------------------------------------------------
__global__ void hist_kernel(const int* __restrict__ si, const int* __restrict__ yi,
                            int* __restrict__ cs, int* __restrict__ cy) {
    int i = blockIdx.x * 256 + threadIdx.x;
    if (i < NROWS) atomicAdd(&cs[si[i]], 1);
    else           atomicAdd(&cy[yi[i - NROWS]], 1);
}

// Per-codebook: prefix-sum of counts (sort bases) + EMA balance scale.
__global__ void scanbal_kernel(const float* __restrict__ cs_in, const float* __restrict__ cy_in,
                               const int* __restrict__ cnt_s, const int* __restrict__ cnt_y,
                               int* __restrict__ base_s, int* __restrict__ base_y,
                               int* __restrict__ cur_s, int* __restrict__ cur_y,
                               float* __restrict__ scale_s, float* __restrict__ scale_y) {
    __shared__ int   sc[1024];
    __shared__ float sf[1024];
    int K = blockIdx.x ? KY : KS;
    const float* csi = blockIdx.x ? cy_in : cs_in;
    const int*   cnt = blockIdx.x ? cnt_y : cnt_s;
    int* base = blockIdx.x ? base_y : base_s;
    int* cur  = blockIdx.x ? cur_y  : cur_s;
    float* scale = blockIdx.x ? scale_y : scale_s;
    int t = threadIdx.x;
    int c = (t < K) ? cnt[t] : 0;
    float ncs = (t < K) ? (csi[t] * 0.99f + 0.01f * (float)c) : 0.f;
    sc[t] = c;
    __syncthreads();
    for (int off = 1; off < 1024; off <<= 1) {
        int v = sc[t] + ((t >= off) ? sc[t - off] : 0);
        __syncthreads();
        sc[t] = v;
        __syncthreads();
    }
    int incl = sc[t];
    sf[t] = ncs;
    __syncthreads();
    for (int s2 = 512; s2 > 0; s2 >>= 1) {
        if (t < s2) sf[t] += sf[t + s2];
        __syncthreads();
    }
    float nsum = sf[0];
    if (t < K) {
        base[t] = incl - c;
        cur[t]  = incl - c;
        float bal = (ncs + 1e-5f) / (nsum + (float)K * 1e-5f) * nsum;
        scale[t] = 1.f / bal;
    }
}

__global__ void scatter_kernel(const int* __restrict__ si, const int* __restrict__ yi,
                               int* __restrict__ cur_s, int* __restrict__ cur_y,
                               int* __restrict__ perm_s, int* __restrict__ perm_y) {
    int i = blockIdx.x * 256 + threadIdx.x;
    if (i < NROWS) { int k = si[i]; int p = atomicAdd(&cur_s[k], 1); perm_s[p] = i; }
    else { int n = i - NROWS; int k = yi[n]; int p = atomicAdd(&cur_y[k], 1); perm_y[p] = n; }
}

// Segmented sum over sorted rows (reads transposed fp32 z).
__global__ void dw_kernel(const float* __restrict__ zf,
                          const int* __restrict__ base_s, const int* __restrict__ cur_s, const int* __restrict__ perm_s,
                          const int* __restrict__ base_y, const int* __restrict__ cur_y, const int* __restrict__ perm_y,
                          float* __restrict__ dw_s, float* __restrict__ dw_y) {
    int id = blockIdx.x, t = threadIdx.x;
    const int *base, *end, *perm; float* dw; int k;
    if (id < KS) { k = id;      base = base_s; end = cur_s; perm = perm_s; dw = dw_s; }
    else         { k = id - KS; base = base_y; end = cur_y; perm = perm_y; dw = dw_y; }
    float acc = 0.f;
    int p0 = base[k], p1 = end[k];
    for (int p = p0; p < p1; ++p) acc += zf[(size_t)perm[p] * 256 + t];
    dw[(size_t)k * 256 + t] = acc;
}

__global__ void embnew_kernel(const float* __restrict__ avg_s, const float* __restrict__ avg_y,
                              const float* __restrict__ dw_s, const float* __restrict__ dw_y,
                              const float* __restrict__ scale_s, const float* __restrict__ scale_y,
                              float* __restrict__ emb_s, float* __restrict__ emb_y) {
    int id = blockIdx.x, t = threadIdx.x;
    if (id < KS) { int i = id * 256 + t; emb_s[i] = (avg_s[i] * 0.99f + 0.01f * dw_s[i]) * scale_s[id]; }
    else { int kk = id - KS; int i = kk * 256 + t; emb_y[i] = (avg_y[i] * 0.99f + 0.01f * dw_y[i]) * scale_y[kk]; }
}

// ---------------------------------------------------------------------------
__global__ void gather_kernel(const float* __restrict__ Se, const float* __restrict__ Ye,
                              const int* __restrict__ sidx, const int* __restrict__ yidx,
                              float* __restrict__ zq, float* __restrict__ disacc) {
    __shared__ float qb[256 * 17];
    __shared__ int   si[16], yi[16];
    __shared__ float red[256];
    const int g  = blockIdx.x;        // b*256 + hw
    const int b  = g >> 8;
    const int hw = g & 255;
    const int t  = threadIdx.x;       // channel
    if (t < 16) {
        int n = b * SPB + hw * 16 + t;
        si[t] = sidx[n];
        yi[t] = yidx[n];
    }
    __syncthreads();
    float ns = 0.f, ny = 0.f, dot = 0.f;
#pragma unroll
    for (int d = 0; d < 16; ++d) {
        float s = Se[(size_t)si[d] * CDIM + t];
        float y = Ye[(size_t)yi[d] * CDIM + t];
        ns  = fmaf(s, s, ns);
        ny  = fmaf(y, y, ny);
        dot = fmaf(s, y, dot);
        qb[t * 17 + d] = 0.5f * (s + y);
    }
    float den = fmaxf(sqrtf(ns), 1e-12f) * fmaxf(sqrtf(ny), 1e-12f);
    float val = dot / den;
    red[t] = val * val;
    __syncthreads();
    for (int s = 128; s > 0; s >>= 1) {
        if (t < s) red[t] += red[t + s];
        __syncthreads();
    }
    if (t == 0) atomicAdd(disacc, red[0]);
    float* zg = zq + (size_t)b * CDIM * SPB + hw * 16;
#pragma unroll
    for (int j = 0; j < 16; ++j) {
        int e = j * 256 + t;
        int c = e >> 4, d = e & 15;
        zg[(size_t)c * SPB + d] = qb[c * 17 + d];
    }
}

__global__ void fin_kernel(const float* __restrict__ disacc, float* __restrict__ out_dis) {
    *out_dis = *disacc * (1.0f / 1048576.0f);
}

// ---------------------------------------------------------------------------
extern "C" void kernel_launch(void* const* d_in, const int* in_sizes, int n_in,
                              void* d_out, int out_size, void* d_ws, size_t ws_size,
                              hipStream_t stream) {
    const float* z     = (const float*)d_in[0];
    const float* Es    = (const float*)d_in[1];
    const float* Ey    = (const float*)d_in[2];
    const float* s_cs  = (const float*)d_in[3];
    const float* y_cs  = (const float*)d_in[4];
    const float* s_avg = (const float*)d_in[5];
    const float* y_avg = (const float*)d_in[6];
    float* out = (float*)d_out;
    char*  w   = (char*)d_ws;

    unsigned short* eimg = (unsigned short*)(w + WB_EIMG);
    float* en2   = (float*)(w + WB_EN2);
    int* idxs_i  = (int*)(w + WB_IDXS_I);
    int* idxy_i  = (int*)(w + WB_IDXY_I);
    int* cnt_s   = (int*)(w + WB_CNT_S);
    int* cnt_y   = (int*)(w + WB_CNT_Y);
    int* r_cnt   = (int*)(w + WB_RESCUE_CNT);
    int* r_list  = (int*)(w + WB_RESCUE_LIST);
    int* base_s  = (int*)(w + WB_BASE_S);
    int* base_y  = (int*)(w + WB_BASE_Y);
    int* cur_s   = (int*)(w + WB_CUR_S);
    int* cur_y   = (int*)(w + WB_CUR_Y);
    float* scale_s = (float*)(w + WB_SCALE_S);
    float* scale_y = (float*)(w + WB_SCALE_Y);
    int* perm_s  = (int*)(w + WB_PERM_S);
    int* perm_y  = (int*)(w + WB_PERM_Y);
    float* dw_s  = (float*)(w + WB_DW_S);
    float* dw_y  = (float*)(w + WB_DW_Y);
    float* emb_s = (float*)(w + WB_EMB_S);
    float* emb_y = (float*)(w + WB_EMB_Y);

    float* zf     = out + OFF_OUT_ZQ;        // zq region reused as fp32 z^T scratch
    float* sidx_f = out + OFF_OUT_SIDX;
    float* yidx_f = out + OFF_OUT_YIDX;

    hipMemsetAsync(w, 0, WB_ZERO_BYTES, stream);

    prep_e<<<KTOT, 64, 0, stream>>>(Es, Ey, eimg, en2);
    prep_z<<<NROWS / 32, 256, 0, stream>>>(z, zf);

    assign_kernel<<<NROWS / 128, 256, 0, stream>>>(z, eimg, en2, sidx_f, yidx_f,
                                                   idxs_i, idxy_i, r_cnt, r_list);
    rescue_kernel<<<256, 256, 0, stream>>>(z, Es, Ey, en2, r_cnt, r_list,
                                           sidx_f, yidx_f, idxs_i, idxy_i);
    hist_kernel<<<2 * NROWS / 256, 256, 0, stream>>>(idxs_i, idxy_i, cnt_s, cnt_y);
    scanbal_kernel<<<2, 1024, 0, stream>>>(s_cs, y_cs, cnt_s, cnt_y, base_s, base_y,
                                           cur_s, cur_y, scale_s, scale_y);
    scatter_kernel<<<2 * NROWS / 256, 256, 0, stream>>>(idxs_i, idxy_i, cur_s, cur_y, perm_s, perm_y);
    dw_kernel<<<KTOT, 256, 0, stream>>>(zf, base_s, cur_s, perm_s, base_y, cur_y, perm_y, dw_s, dw_y);
    embnew_kernel<<<KTOT, 256, 0, stream>>>(s_avg, y_avg, dw_s, dw_y, scale_s, scale_y, emb_s, emb_y);
    gather_kernel<<<4096, 256, 0, stream>>>(emb_s, emb_y, idxs_i, idxy_i,
                                            out + OFF_OUT_ZQ, (float*)(w + WB_DISACC));
    fin_kernel<<<1, 1, 0, stream>>>((float*)(w + WB_DISACC), out + OFF_OUT_DIS);
}

// Round 3
// 534.235 us; speedup vs baseline: 10.7079x; 2.6068x over previous
//
#include <hip/hip_runtime.h>
#include <float.h>

// Problem constants
#define NROWS 65536      // B*H*W*D
#define CDIM  256
#define KS    1024
#define KY    512
#define KTOT  1536
#define SPB   4096       // H*W*D per batch
#define TAU   0.05f
#define RESCUE_CAP 8192

// ---- workspace byte offsets ----
#define WB_CNT_S       0         // 1024 int
#define WB_CNT_Y       4096      // 512 int
#define WB_RESCUE_CNT  6144      // 1 int
#define WB_DISACC      6148      // 1 float
#define WB_DW_S        6400      // 1024*256 f32
#define WB_DW_Y        1054976   // 512*256 f32
#define WB_ZERO_BYTES  1579264   // memset [0, here)
#define WB_EIMG        1579264   // 24 chunks * 65536 B (ushort bf16 image)
#define WB_EN2         3152128   // 1536 f32
#define WB_IDXS_I      3158272   // 65536 int
#define WB_IDXY_I      3420416   // 65536 int
#define WB_RESCUE_LIST 3682560   // 8192 int
#define WB_BASE_S      3715328   // 1024 int
#define WB_BASE_Y      3719424   // 512 int
#define WB_CUR_S       3721472   // 1024 int
#define WB_CUR_Y       3725568   // 512 int
#define WB_SCALE_S     3727616   // 1024 f32
#define WB_SCALE_Y     3731712   // 512 f32
#define WB_PERM_S      3733760   // 65536 int
#define WB_PERM_Y      3995904   // 65536 int
#define WB_KSORT_S     4258048   // 65536 int
#define WB_KSORT_Y     4520192   // 65536 int
#define WB_EMB_S       4782336   // 1024*256 f32
#define WB_EMB_Y       5830912   // 512*256 f32

// ---- output float offsets ----
#define OFF_OUT_ZQ   0
#define OFF_OUT_DIS  16777216
#define OFF_OUT_SIDX 16777217
#define OFF_OUT_YIDX 16842753

typedef __attribute__((ext_vector_type(8)))  __bf16 bf16x8;
typedef __attribute__((ext_vector_type(16))) float  f32x16;
typedef __attribute__((ext_vector_type(8)))  unsigned short ushort8;

__device__ __forceinline__ unsigned int bf16rne(float f) {
    unsigned int u = __float_as_uint(f);
    return (u + 0x7fffu + ((u >> 16) & 1u)) >> 16;
}

// ---------------------------------------------------------------------------
// Codebook prep: combined (structure ++ style) -> bf16 hi/lo fragment-linear
// LDS images (chunk = 64 codes = 64KB) + |e|^2 fp32. One wave per code row.
__global__ void prep_e(const float* __restrict__ Es, const float* __restrict__ Ey,
                       unsigned short* __restrict__ eimg, float* __restrict__ en2) {
    int k = blockIdx.x;            // 0..1535 global code
    int lane = threadIdx.x;        // 64
    const float* E = (k < KS) ? (Es + (size_t)k * CDIM) : (Ey + (size_t)(k - KS) * CDIM);
    float4 v = *(const float4*)(E + lane * 4);
    float nrm = v.x * v.x + v.y * v.y + v.z * v.z + v.w * v.w;
#pragma unroll
    for (int off = 32; off > 0; off >>= 1) nrm += __shfl_down(nrm, off);
    if (lane == 0) en2[k] = nrm;

    unsigned int h0 = bf16rne(v.x), h1 = bf16rne(v.y), h2 = bf16rne(v.z), h3 = bf16rne(v.w);
    float r0 = v.x - __uint_as_float(h0 << 16);
    float r1 = v.y - __uint_as_float(h1 << 16);
    float r2 = v.z - __uint_as_float(h2 << 16);
    float r3 = v.w - __uint_as_float(h3 << 16);
    unsigned int l0 = bf16rne(r0), l1 = bf16rne(r1), l2 = bf16rne(r2), l3 = bf16rne(r3);
    uint2 hp = make_uint2(h0 | (h1 << 16), h2 | (h3 << 16));
    uint2 lp = make_uint2(l0 | (l1 << 16), l2 | (l3 << 16));

    int t = k >> 6, kk = k & 63, ktile = kk >> 5, kin = kk & 31;
    int cc = lane >> 2, g = (lane & 3) >> 1, j0 = (lane & 1) * 4;
    // fragment order: (ktile, cc, part) blocks of 1024B; lane slot = kin + 32*g
    size_t base = (size_t)t * 32768 + (size_t)(((ktile * 16 + cc) * 2 + 0) * 512)
                + (size_t)((kin + 32 * g) * 8 + j0);          // ushort units
    *(uint2*)(eimg + base)        = hp;
    *(uint2*)(eimg + base + 512)  = lp;                        // lo part block
}

// ---------------------------------------------------------------------------
// Transpose z -> zf[n][c] fp32 (written into d_out zq region as scratch).
__global__ void prep_z(const float* __restrict__ z, float* __restrict__ zf) {
    __shared__ float Zs[32][257];
    int blk = blockIdx.x;          // 2048
    int n0 = blk * 32, b = n0 >> 12, s0 = n0 & 4095;
    int t = threadIdx.x;
    const float* zb = z + (size_t)b * CDIM * SPB + s0;
#pragma unroll
    for (int i = 0; i < 32; ++i) {
        int l = i * 256 + t;       // c*32 + s
        int c = l >> 5, s = l & 31;
        Zs[s][c] = zb[(size_t)c * SPB + s];
    }
    __syncthreads();
#pragma unroll
    for (int j = 0; j < 8; ++j) {
        int gid = j * 256 + t;     // nl*64 + fg
        int nl = gid >> 6, fg = gid & 63;
        float4 v = *(const float4*)(&Zs[nl][fg * 4]);
        *(float4*)(&zf[(size_t)(n0 + nl) * 256 + fg * 4]) = v;
    }
}

// ---------------------------------------------------------------------------
// MFMA assign: per block 128 rows (4 waves x 32), loop both codebooks.
// 3-product bf16 split: hh + hl + lh (ll dropped; err ~1e-4 << TAU).
__launch_bounds__(256, 2)
__global__ void assign_kernel(const float* __restrict__ z, const unsigned short* __restrict__ eimg,
                              const float* __restrict__ en2,
                              float* __restrict__ sidx_f, float* __restrict__ yidx_f,
                              int* __restrict__ sidx_i, int* __restrict__ yidx_i,
                              int* __restrict__ rescue_cnt, int* __restrict__ rescue_list) {
    __shared__ unsigned short sh[32768];   // 64KB chunk image
    const int tid = threadIdx.x, wave = tid >> 6, lane = tid & 63;
    const int n0 = blockIdx.x * 128;
    const int b = n0 >> 12;
    const int myrow_s = (n0 & 4095) + wave * 32 + (lane & 31);
    const float* zb = z + (size_t)b * CDIM * SPB;
    const int g8 = (lane >> 5) * 8;

    // A fragments (register-resident): 16 c-chunks x {hi,lo}
    bf16x8 Ah[16], Al[16];
#pragma unroll
    for (int cc = 0; cc < 16; ++cc) {
        ushort8 uh, ul;
#pragma unroll
        for (int j = 0; j < 8; ++j) {
            float f = zb[(size_t)(cc * 16 + g8 + j) * SPB + myrow_s];
            unsigned int h = bf16rne(f);
            float r = f - __uint_as_float(h << 16);
            uh[j] = (unsigned short)h;
            ul[j] = (unsigned short)bf16rne(r);
        }
        Ah[cc] = __builtin_bit_cast(bf16x8, uh);
        Al[cc] = __builtin_bit_cast(bf16x8, ul);
    }

    for (int book = 0; book < 2; ++book) {
        const int t0 = book ? 16 : 0, t1 = book ? 24 : 16, kbase = book ? KS : 0;
        float minv[16], minv2[16]; int mini[16];
#pragma unroll
        for (int i = 0; i < 16; ++i) { minv[i] = FLT_MAX; minv2[i] = FLT_MAX; mini[i] = 0; }

        for (int t = t0; t < t1; ++t) {
            // stage 64KB chunk (reg-staged, coalesced)
            {
                const float4* gs = (const float4*)((const char*)eimg + (size_t)t * 65536) + tid;
                float4* ls = (float4*)((char*)sh) + tid;
#pragma unroll
                for (int ib = 0; ib < 4; ++ib) {
                    float4 tmp0 = gs[(ib * 4 + 0) * 256];
                    float4 tmp1 = gs[(ib * 4 + 1) * 256];
                    float4 tmp2 = gs[(ib * 4 + 2) * 256];
                    float4 tmp3 = gs[(ib * 4 + 3) * 256];
                    ls[(ib * 4 + 0) * 256] = tmp0;
                    ls[(ib * 4 + 1) * 256] = tmp1;
                    ls[(ib * 4 + 2) * 256] = tmp2;
                    ls[(ib * 4 + 3) * 256] = tmp3;
                }
            }
            __syncthreads();

            const int kb = t * 64 + (lane & 31);
            const float en0 = en2[kb], en1 = en2[kb + 32];
            f32x16 acc0 = {}, acc1 = {};
            const char* shb = (const char*)sh + lane * 16;
#pragma unroll
            for (int cc = 0; cc < 16; ++cc) {
                bf16x8 bh0 = *(const bf16x8*)(shb + (size_t)((cc * 2 + 0) * 1024));
                bf16x8 bl0 = *(const bf16x8*)(shb + (size_t)((cc * 2 + 1) * 1024));
                bf16x8 bh1 = *(const bf16x8*)(shb + (size_t)(((16 + cc) * 2 + 0) * 1024));
                bf16x8 bl1 = *(const bf16x8*)(shb + (size_t)(((16 + cc) * 2 + 1) * 1024));
                acc0 = __builtin_amdgcn_mfma_f32_32x32x16_bf16(Ah[cc], bh0, acc0, 0, 0, 0);
                acc1 = __builtin_amdgcn_mfma_f32_32x32x16_bf16(Ah[cc], bh1, acc1, 0, 0, 0);
                acc0 = __builtin_amdgcn_mfma_f32_32x32x16_bf16(Ah[cc], bl0, acc0, 0, 0, 0);
                acc1 = __builtin_amdgcn_mfma_f32_32x32x16_bf16(Ah[cc], bl1, acc1, 0, 0, 0);
                acc0 = __builtin_amdgcn_mfma_f32_32x32x16_bf16(Al[cc], bh0, acc0, 0, 0, 0);
                acc1 = __builtin_amdgcn_mfma_f32_32x32x16_bf16(Al[cc], bh1, acc1, 0, 0, 0);
            }
#pragma unroll
            for (int i = 0; i < 16; ++i) {
                float d0 = fmaf(-2.f, acc0[i], en0);
                if (d0 < minv[i]) { minv2[i] = minv[i]; minv[i] = d0; mini[i] = kb; }
                else minv2[i] = fminf(minv2[i], d0);
                float d1 = fmaf(-2.f, acc1[i], en1);
                if (d1 < minv[i]) { minv2[i] = minv[i]; minv[i] = d1; mini[i] = kb + 32; }
                else minv2[i] = fminf(minv2[i], d1);
            }
            __syncthreads();
        }

        // cross-lane argmin over the 32 lanes sharing each output row
        float* idx_f = book ? yidx_f : sidx_f;
        int*   idx_i = book ? yidx_i : sidx_i;
#pragma unroll
        for (int i = 0; i < 16; ++i) {
            float v1 = minv[i], v2 = minv2[i]; int k1 = mini[i];
#pragma unroll
            for (int m = 16; m >= 1; m >>= 1) {
                float ov1 = __shfl_xor(v1, m);
                int   ok1 = __shfl_xor(k1, m);
                float ov2 = __shfl_xor(v2, m);
                if (ov1 < v1 || (ov1 == v1 && ok1 < k1)) { v2 = fminf(ov2, v1); v1 = ov1; k1 = ok1; }
                else v2 = fminf(v2, fminf(ov1, ov2));
            }
            if ((lane & 31) == 0) {
                int r = (i & 3) + 8 * (i >> 2) + 4 * (lane >> 5);
                int n = n0 + wave * 32 + r;
                int kw = k1 - kbase;
                idx_f[n] = (float)kw;
                idx_i[n] = kw;
                if (v2 - v1 < TAU) {
                    int p = atomicAdd(rescue_cnt, 1);
                    if (p < RESCUE_CAP) rescue_list[p] = n | (book << 24);
                }
            }
        }
    }
}

// ---------------------------------------------------------------------------
// Exact-fp32 re-argmin for near-tie rows.
__global__ void rescue_kernel(const float* __restrict__ z, const float* __restrict__ Es,
                              const float* __restrict__ Ey, const float* __restrict__ en2,
                              const int* __restrict__ rescue_cnt, const int* __restrict__ rescue_list,
                              float* __restrict__ sidx_f, float* __restrict__ yidx_f,
                              int* __restrict__ sidx_i, int* __restrict__ yidx_i) {
    __shared__ float zrow[256];
    __shared__ float rv[256];
    __shared__ int   rk[256];
    int cnt = *rescue_cnt; if (cnt > RESCUE_CAP) cnt = RESCUE_CAP;
    int t = threadIdx.x;
    for (int e = blockIdx.x; e < cnt; e += gridDim.x) {
        int ent = rescue_list[e];
        int n = ent & 0x00FFFFFF, book = ent >> 24;
        int b = n >> 12, s = n & 4095;
        __syncthreads();
        zrow[t] = z[((size_t)b * CDIM + t) * SPB + s];
        __syncthreads();
        int K = book ? KY : KS, kb = book ? KS : 0;
        const float* E = book ? Ey : Es;
        float bv = FLT_MAX; int bk = 0;
        for (int k = t; k < K; k += 256) {
            const float* er = E + (size_t)k * CDIM;
            float dot = 0.f;
            for (int c = 0; c < 256; ++c) dot = fmaf(zrow[c], er[c], dot);
            float d = en2[kb + k] - 2.f * dot;
            if (d < bv) { bv = d; bk = k; }
        }
        rv[t] = bv; rk[t] = bk;
        __syncthreads();
        for (int s2 = 128; s2 > 0; s2 >>= 1) {
            if (t < s2) {
                float ov = rv[t + s2]; int ok = rk[t + s2];
                if (ov < rv[t] || (ov == rv[t] && ok < rk[t])) { rv[t] = ov; rk[t] = ok; }
            }
            __syncthreads();
        }
        if (t == 0) {
            if (book) { yidx_f[n] = (float)rk[0]; yidx_i[n] = rk[0]; }
            else      { sidx_f[n] = (float)rk[0]; sidx_i[n] = rk[0]; }
        }
    }
}

// ---------------------------------------------------------------------------
__global__ void hist_kernel(const int* __restrict__ si, const int* __restrict__ yi,
                            int* __restrict__ cs, int* __restrict__ cy) {
    int i = blockIdx.x * 256 + threadIdx.x;
    if (i < NROWS) atomicAdd(&cs[si[i]], 1);
    else           atomicAdd(&cy[yi[i - NROWS]], 1);
}

// Per-codebook: prefix-sum of counts (sort bases) + EMA balance scale.
__global__ void scanbal_kernel(const float* __restrict__ cs_in, const float* __restrict__ cy_in,
                               const int* __restrict__ cnt_s, const int* __restrict__ cnt_y,
                               int* __restrict__ base_s, int* __restrict__ base_y,
                               int* __restrict__ cur_s, int* __restrict__ cur_y,
                               float* __restrict__ scale_s, float* __restrict__ scale_y) {
    __shared__ int   sc[1024];
    __shared__ float sf[1024];
    int K = blockIdx.x ? KY : KS;
    const float* csi = blockIdx.x ? cy_in : cs_in;
    const int*   cnt = blockIdx.x ? cnt_y : cnt_s;
    int* base = blockIdx.x ? base_y : base_s;
    int* cur  = blockIdx.x ? cur_y  : cur_s;
    float* scale = blockIdx.x ? scale_y : scale_s;
    int t = threadIdx.x;
    int c = (t < K) ? cnt[t] : 0;
    float ncs = (t < K) ? (csi[t] * 0.99f + 0.01f * (float)c) : 0.f;
    sc[t] = c;
    __syncthreads();
    for (int off = 1; off < 1024; off <<= 1) {
        int v = sc[t] + ((t >= off) ? sc[t - off] : 0);
        __syncthreads();
        sc[t] = v;
        __syncthreads();
    }
    int incl = sc[t];
    sf[t] = ncs;
    __syncthreads();
    for (int s2 = 512; s2 > 0; s2 >>= 1) {
        if (t < s2) sf[t] += sf[t + s2];
        __syncthreads();
    }
    float nsum = sf[0];
    if (t < K) {
        base[t] = incl - c;
        cur[t]  = incl - c;
        float bal = (ncs + 1e-5f) / (nsum + (float)K * 1e-5f) * nsum;
        scale[t] = 1.f / bal;
    }
}

__global__ void scatter_kernel(const int* __restrict__ si, const int* __restrict__ yi,
                               int* __restrict__ cur_s, int* __restrict__ cur_y,
                               int* __restrict__ perm_s, int* __restrict__ perm_y,
                               int* __restrict__ ksort_s, int* __restrict__ ksort_y) {
    int i = blockIdx.x * 256 + threadIdx.x;
    if (i < NROWS) {
        int k = si[i]; int p = atomicAdd(&cur_s[k], 1);
        perm_s[p] = i; ksort_s[p] = k;
    } else {
        int n = i - NROWS; int k = yi[n]; int p = atomicAdd(&cur_y[k], 1);
        perm_y[p] = n; ksort_y[p] = k;
    }
}

// ---------------------------------------------------------------------------
// Chunked segmented sum over sorted rows: block = 64 sorted positions,
// thread = channel. Runs flushed with fp32 atomics (boundary partials add up).
__global__ void dw_kernel(const float* __restrict__ zf,
                          const int* __restrict__ perm_s, const int* __restrict__ ksort_s,
                          const int* __restrict__ perm_y, const int* __restrict__ ksort_y,
                          float* __restrict__ dw_s, float* __restrict__ dw_y) {
    __shared__ int keys[65];
    __shared__ int rows[64];
    const int t = threadIdx.x;
    int blk = blockIdx.x;
    const int* perm; const int* ks; float* dw; int p0;
    if (blk < NROWS / 64) { perm = perm_s; ks = ksort_s; dw = dw_s; p0 = blk * 64; }
    else                  { perm = perm_y; ks = ksort_y; dw = dw_y; p0 = (blk - NROWS / 64) * 64; }
    if (t < 64) { keys[t] = ks[p0 + t]; rows[t] = perm[p0 + t]; }
    if (t == 64) keys[64] = -1;   // sentinel: force flush at chunk end
    __syncthreads();
    float acc = 0.f;
#pragma unroll 8
    for (int j = 0; j < 64; ++j) {
        acc += zf[(size_t)rows[j] * 256 + t];
        if (keys[j + 1] != keys[j]) {
            atomicAdd(&dw[(size_t)keys[j] * 256 + t], acc);
            acc = 0.f;
        }
    }
}

__global__ void embnew_kernel(const float* __restrict__ avg_s, const float* __restrict__ avg_y,
                              const float* __restrict__ dw_s, const float* __restrict__ dw_y,
                              const float* __restrict__ scale_s, const float* __restrict__ scale_y,
                              float* __restrict__ emb_s, float* __restrict__ emb_y) {
    int id = blockIdx.x, t = threadIdx.x;
    if (id < KS) { int i = id * 256 + t; emb_s[i] = (avg_s[i] * 0.99f + 0.01f * dw_s[i]) * scale_s[id]; }
    else { int kk = id - KS; int i = kk * 256 + t; emb_y[i] = (avg_y[i] * 0.99f + 0.01f * dw_y[i]) * scale_y[kk]; }
}

// ---------------------------------------------------------------------------
__global__ void gather_kernel(const float* __restrict__ Se, const float* __restrict__ Ye,
                              const int* __restrict__ sidx, const int* __restrict__ yidx,
                              float* __restrict__ zq, float* __restrict__ disacc) {
    __shared__ float qb[256 * 17];
    __shared__ int   si[16], yi[16];
    __shared__ float red[256];
    const int g  = blockIdx.x;        // b*256 + hw
    const int b  = g >> 8;
    const int hw = g & 255;
    const int t  = threadIdx.x;       // channel
    if (t < 16) {
        int n = b * SPB + hw * 16 + t;
        si[t] = sidx[n];
        yi[t] = yidx[n];
    }
    __syncthreads();
    float ns = 0.f, ny = 0.f, dot = 0.f;
#pragma unroll
    for (int d = 0; d < 16; ++d) {
        float s = Se[(size_t)si[d] * CDIM + t];
        float y = Ye[(size_t)yi[d] * CDIM + t];
        ns  = fmaf(s, s, ns);
        ny  = fmaf(y, y, ny);
        dot = fmaf(s, y, dot);
        qb[t * 17 + d] = 0.5f * (s + y);
    }
    float den = fmaxf(sqrtf(ns), 1e-12f) * fmaxf(sqrtf(ny), 1e-12f);
    float val = dot / den;
    red[t] = val * val;
    __syncthreads();
    for (int s = 128; s > 0; s >>= 1) {
        if (t < s) red[t] += red[t + s];
        __syncthreads();
    }
    if (t == 0) atomicAdd(disacc, red[0]);
    float* zg = zq + (size_t)b * CDIM * SPB + hw * 16;
#pragma unroll
    for (int j = 0; j < 16; ++j) {
        int e = j * 256 + t;
        int c = e >> 4, d = e & 15;
        zg[(size_t)c * SPB + d] = qb[c * 17 + d];
    }
}

__global__ void fin_kernel(const float* __restrict__ disacc, float* __restrict__ out_dis) {
    *out_dis = *disacc * (1.0f / 1048576.0f);
}

// ---------------------------------------------------------------------------
extern "C" void kernel_launch(void* const* d_in, const int* in_sizes, int n_in,
                              void* d_out, int out_size, void* d_ws, size_t ws_size,
                              hipStream_t stream) {
    const float* z     = (const float*)d_in[0];
    const float* Es    = (const float*)d_in[1];
    const float* Ey    = (const float*)d_in[2];
    const float* s_cs  = (const float*)d_in[3];
    const float* y_cs  = (const float*)d_in[4];
    const float* s_avg = (const float*)d_in[5];
    const float* y_avg = (const float*)d_in[6];
    float* out = (float*)d_out;
    char*  w   = (char*)d_ws;

    unsigned short* eimg = (unsigned short*)(w + WB_EIMG);
    float* en2   = (float*)(w + WB_EN2);
    int* idxs_i  = (int*)(w + WB_IDXS_I);
    int* idxy_i  = (int*)(w + WB_IDXY_I);
    int* cnt_s   = (int*)(w + WB_CNT_S);
    int* cnt_y   = (int*)(w + WB_CNT_Y);
    int* r_cnt   = (int*)(w + WB_RESCUE_CNT);
    int* r_list  = (int*)(w + WB_RESCUE_LIST);
    int* base_s  = (int*)(w + WB_BASE_S);
    int* base_y  = (int*)(w + WB_BASE_Y);
    int* cur_s   = (int*)(w + WB_CUR_S);
    int* cur_y   = (int*)(w + WB_CUR_Y);
    float* scale_s = (float*)(w + WB_SCALE_S);
    float* scale_y = (float*)(w + WB_SCALE_Y);
    int* perm_s  = (int*)(w + WB_PERM_S);
    int* perm_y  = (int*)(w + WB_PERM_Y);
    int* ksort_s = (int*)(w + WB_KSORT_S);
    int* ksort_y = (int*)(w + WB_KSORT_Y);
    float* dw_s  = (float*)(w + WB_DW_S);
    float* dw_y  = (float*)(w + WB_DW_Y);
    float* emb_s = (float*)(w + WB_EMB_S);
    float* emb_y = (float*)(w + WB_EMB_Y);

    float* zf     = out + OFF_OUT_ZQ;        // zq region reused as fp32 z^T scratch
    float* sidx_f = out + OFF_OUT_SIDX;
    float* yidx_f = out + OFF_OUT_YIDX;

    hipMemsetAsync(w, 0, WB_ZERO_BYTES, stream);

    prep_e<<<KTOT, 64, 0, stream>>>(Es, Ey, eimg, en2);
    prep_z<<<NROWS / 32, 256, 0, stream>>>(z, zf);

    assign_kernel<<<NROWS / 128, 256, 0, stream>>>(z, eimg, en2, sidx_f, yidx_f,
                                                   idxs_i, idxy_i, r_cnt, r_list);
    rescue_kernel<<<256, 256, 0, stream>>>(z, Es, Ey, en2, r_cnt, r_list,
                                           sidx_f, yidx_f, idxs_i, idxy_i);
    hist_kernel<<<2 * NROWS / 256, 256, 0, stream>>>(idxs_i, idxy_i, cnt_s, cnt_y);
    scanbal_kernel<<<2, 1024, 0, stream>>>(s_cs, y_cs, cnt_s, cnt_y, base_s, base_y,
                                           cur_s, cur_y, scale_s, scale_y);
    scatter_kernel<<<2 * NROWS / 256, 256, 0, stream>>>(idxs_i, idxy_i, cur_s, cur_y,
                                                        perm_s, perm_y, ksort_s, ksort_y);
    dw_kernel<<<2 * NROWS / 64, 256, 0, stream>>>(zf, perm_s, ksort_s, perm_y, ksort_y, dw_s, dw_y);
    embnew_kernel<<<KTOT, 256, 0, stream>>>(s_avg, y_avg, dw_s, dw_y, scale_s, scale_y, emb_s, emb_y);
    gather_kernel<<<4096, 256, 0, stream>>>(emb_s, emb_y, idxs_i, idxy_i,
                                            out + OFF_OUT_ZQ, (float*)(w + WB_DISACC));
    fin_kernel<<<1, 1, 0, stream>>>((float*)(w + WB_DISACC), out + OFF_OUT_DIS);
}

// Round 4
// 489.693 us; speedup vs baseline: 11.6819x; 1.0910x over previous
//
#include <hip/hip_runtime.h>
#include <float.h>

// Problem constants
#define NROWS 65536      // B*H*W*D
#define CDIM  256
#define KS    1024
#define KY    512
#define KTOT  1536
#define SPB   4096       // H*W*D per batch

// ---- workspace byte offsets ----
#define WB_CNT_S       0         // 1024 int
#define WB_CNT_Y       4096      // 512 int
#define WB_RESCUE_CNT  6144      // 2 int
#define WB_DISACC      6152      // 1 float
#define WB_DW_S        6400      // 1024*256 f32
#define WB_DW_Y        1054976   // 512*256 f32
#define WB_ZERO_BYTES  1579264   // memset [0, here)
#define WB_EIMG        1579264   // 48 chunks * 16384 B (fp16 image)
#define WB_EN2         2365696   // 1536 f32
#define WB_IDXS_I      2371840   // 65536 int
#define WB_IDXY_I      2633984   // 65536 int
#define WB_RLIST_S     2896128   // 65536 int
#define WB_RLIST_Y     3158272   // 65536 int
#define WB_BASE_S      3420416   // 1024 int
#define WB_BASE_Y      3424512   // 512 int
#define WB_CUR_S       3426560   // 1024 int
#define WB_CUR_Y       3430656   // 512 int
#define WB_SCALE_S     3432704   // 1024 f32
#define WB_SCALE_Y     3436800   // 512 f32
#define WB_PERM_S      3438848   // 65536 int
#define WB_PERM_Y      3700992   // 65536 int
#define WB_KSORT_S     3963136   // 65536 int
#define WB_KSORT_Y     4225280   // 65536 int
#define WB_EMB_S       4487424   // 1024*256 f32
#define WB_EMB_Y       5536000   // 512*256 f32

// ---- output float offsets ----
#define OFF_OUT_ZQ   0
#define OFF_OUT_DIS  16777216
#define OFF_OUT_SIDX 16777217
#define OFF_OUT_YIDX 16842753

typedef __attribute__((ext_vector_type(8)))  _Float16 f16x8;
typedef __attribute__((ext_vector_type(16))) float    f32x16;

__device__ __forceinline__ unsigned int umn(unsigned int a, unsigned int b) { return a < b ? a : b; }
__device__ __forceinline__ unsigned int umx(unsigned int a, unsigned int b) { return a > b ? a : b; }

// ---------------------------------------------------------------------------
// Codebook prep: combined (structure ++ style) -> fp16 fragment-linear image
// (chunk = 32 codes = 16KB) + exact fp32 |e|^2. One 64-lane wave per code.
__global__ void prep_e(const float* __restrict__ Es, const float* __restrict__ Ey,
                       unsigned short* __restrict__ eimg, float* __restrict__ en2) {
    int k = blockIdx.x;            // 0..1535 global code
    int lane = threadIdx.x;        // 64
    const float* E = (k < KS) ? (Es + (size_t)k * CDIM) : (Ey + (size_t)(k - KS) * CDIM);
    float4 v = *(const float4*)(E + lane * 4);
    float nrm = v.x * v.x + v.y * v.y + v.z * v.z + v.w * v.w;
#pragma unroll
    for (int off = 32; off > 0; off >>= 1) nrm += __shfl_down(nrm, off);
    if (lane == 0) en2[k] = nrm;

    unsigned short q0 = __builtin_bit_cast(unsigned short, (_Float16)v.x);
    unsigned short q1 = __builtin_bit_cast(unsigned short, (_Float16)v.y);
    unsigned short q2 = __builtin_bit_cast(unsigned short, (_Float16)v.z);
    unsigned short q3 = __builtin_bit_cast(unsigned short, (_Float16)v.w);
    uint2 hp = make_uint2((unsigned)q0 | ((unsigned)q1 << 16),
                          (unsigned)q2 | ((unsigned)q3 << 16));

    int t = k >> 5, kin = k & 31;
    int cc = lane >> 2, g = (lane >> 1) & 1, j0 = (lane & 1) * 4;
    // chunk t: 16 cc-blocks of 1024B; lane slot = kin + 32*g, 8 fp16 each
    size_t base = (size_t)t * 8192 + (size_t)(cc * 512) + (size_t)((kin + 32 * g) * 8 + j0);
    *(uint2*)(eimg + base) = hp;
}

// ---------------------------------------------------------------------------
// Transpose z -> zf[n][c] fp32 (written into d_out zq region as scratch).
__global__ void prep_z(const float* __restrict__ z, float* __restrict__ zf) {
    __shared__ float Zs[32][257];
    int blk = blockIdx.x;          // 2048
    int n0 = blk * 32, b = n0 >> 12, s0 = n0 & 4095;
    int t = threadIdx.x;
    const float* zb = z + (size_t)b * CDIM * SPB + s0;
#pragma unroll
    for (int i = 0; i < 32; ++i) {
        int l = i * 256 + t;       // c*32 + s
        int c = l >> 5, s = l & 31;
        Zs[s][c] = zb[(size_t)c * SPB + s];
    }
    __syncthreads();
#pragma unroll
    for (int j = 0; j < 8; ++j) {
        int gid = j * 256 + t;     // nl*64 + fg
        int nl = gid >> 6, fg = gid & 63;
        float4 v = *(const float4*)(&Zs[nl][fg * 4]);
        *(float4*)(&zf[(size_t)(n0 + nl) * 256 + fg * 4]) = v;
    }
}

// ---------------------------------------------------------------------------
// MFMA assign: 128 threads = 2 waves x 32 rows; fp16 single-product distance
// estimate over both codebooks; tag-packed argmin; fused count histogram.
__global__ void assign_kernel(const float* __restrict__ z, const unsigned short* __restrict__ eimg,
                              const float* __restrict__ en2,
                              float* __restrict__ sidx_f, float* __restrict__ yidx_f,
                              int* __restrict__ sidx_i, int* __restrict__ yidx_i,
                              int* __restrict__ cnt_s, int* __restrict__ cnt_y,
                              int* __restrict__ rescue_cnt,
                              int* __restrict__ rlist_s, int* __restrict__ rlist_y) {
    __shared__ unsigned short sh[8192];    // 16KB chunk image
    const int tid = threadIdx.x, wave = tid >> 6, lane = tid & 63;
    const int row32 = lane & 31;
    const int n0 = blockIdx.x * 64;
    const int b = n0 >> 12;
    const int myrow_s = (n0 & 4095) + wave * 32 + row32;
    const float* zb = z + (size_t)b * CDIM * SPB;
    const int g8 = (lane >> 5) * 8;

    // A fragments: 16 c-chunks, fp16
    f16x8 Ah[16];
#pragma unroll
    for (int cc = 0; cc < 16; ++cc) {
        f16x8 a;
#pragma unroll
        for (int j = 0; j < 8; ++j)
            a[j] = (_Float16)zb[(size_t)(cc * 16 + g8 + j) * SPB + myrow_s];
        Ah[cc] = a;
    }

    unsigned int m1[16], m2[16];
#pragma unroll
    for (int i = 0; i < 16; ++i) { m1[i] = 0xFFFFFFFFu; m2[i] = 0xFFFFFFFFu; }

    for (int t = 0; t < 48; ++t) {
        // stage 16KB chunk via global_load_lds: 2 waves x 8 x 1KB
        {
            const char* gs = (const char*)eimg + (size_t)t * 16384 + wave * 8192 + lane * 16;
            char* ls = (char*)sh + wave * 8192;
#pragma unroll
            for (int i = 0; i < 8; ++i)
                __builtin_amdgcn_global_load_lds(
                    (const __attribute__((address_space(1))) void*)(gs + i * 1024),
                    (__attribute__((address_space(3))) void*)(ls + i * 1024), 16, 0, 0);
        }
        __syncthreads();

        const int kglob = t * 32 + row32;
        const float en0 = en2[kglob] + 512.0f;   // keep tagged distance positive, exp-normalized
        f32x16 acc = {};
        const char* shb = (const char*)sh + lane * 16;
#pragma unroll
        for (int cc = 0; cc < 16; ++cc) {
            f16x8 bh = *(const f16x8*)(shb + cc * 1024);
            acc = __builtin_amdgcn_mfma_f32_32x32x16_f16(Ah[cc], bh, acc, 0, 0, 0);
        }
        const unsigned int tag = (unsigned int)kglob;   // 11 bits
#pragma unroll
        for (int i = 0; i < 16; ++i) {
            float d = fmaf(-2.f, acc[i], en0);
            unsigned int du = (__float_as_uint(d) & 0xFFFFF800u) | tag;
            m2[i] = umn(m2[i], umx(m1[i], du));
            m1[i] = umn(m1[i], du);
        }
        __syncthreads();

        if (t == 31 || t == 47) {
            const int book = (t == 47);
            float* fo = book ? yidx_f : sidx_f;
            int*   io = book ? yidx_i : sidx_i;
            int*   cb = book ? cnt_y : cnt_s;
            int*   rl = book ? rlist_y : rlist_s;
#pragma unroll
            for (int i = 0; i < 16; ++i) {
                unsigned int v1 = m1[i], v2 = m2[i];
#pragma unroll
                for (int m = 16; m >= 1; m >>= 1) {
                    unsigned int o1 = (unsigned int)__shfl_xor((int)v1, m);
                    unsigned int o2 = (unsigned int)__shfl_xor((int)v2, m);
                    v2 = umn(umn(v2, o2), umx(v1, o1));
                    v1 = umn(v1, o1);
                }
                if (row32 == 0) {
                    int kg = (int)(v1 & 0x7FFu);
                    int kw = kg - (book ? KS : 0);
                    int r = (i & 3) + 8 * (i >> 2) + 4 * (lane >> 5);
                    int n = n0 + wave * 32 + r;
                    fo[n] = (float)kw;
                    io[n] = kw;
                    atomicAdd(&cb[kw], 1);
                    if ((v1 >> 11) + 3 > (v2 >> 11)) {   // masked margin <= 2 units -> exact rescue
                        int p = atomicAdd(&rescue_cnt[book], 1);
                        if (p < 65536) rl[p] = n;
                    }
                }
            }
            if (t == 31) {
#pragma unroll
                for (int i = 0; i < 16; ++i) { m1[i] = 0xFFFFFFFFu; m2[i] = 0xFFFFFFFFu; }
            }
        }
    }
}

// ---------------------------------------------------------------------------
// Exact-fp32 re-argmin for near-tie rows. 4 entries per block-iteration
// (shares codebook row reads); fixes idx AND count histogram when changed.
__global__ void rescue_kernel(const float* __restrict__ z, const float* __restrict__ E,
                              const float* __restrict__ en2k, int K,
                              const int* __restrict__ rcnt, const int* __restrict__ rlist,
                              float* __restrict__ idx_f, int* __restrict__ idx_i,
                              int* __restrict__ cnt) {
    __shared__ float zrow[4][256];
    __shared__ float rv[4][256];
    __shared__ int   rk[4][256];
    __shared__ int   ns[4];
    const int cnt_e = *rcnt;
    const int t = threadIdx.x;
    for (int base = blockIdx.x * 4; base < cnt_e; base += 256 * 4) {
        int ne = cnt_e - base; if (ne > 4) ne = 4;
        __syncthreads();
        if (t < ne) ns[t] = rlist[base + t];
        __syncthreads();
        for (int e = 0; e < ne; ++e) {
            int n = ns[e]; int b = n >> 12, s = n & 4095;
            zrow[e][t] = z[((size_t)b * CDIM + t) * SPB + s];
        }
        __syncthreads();
        float bv[4] = { FLT_MAX, FLT_MAX, FLT_MAX, FLT_MAX };
        int   bk[4] = { 0, 0, 0, 0 };
        for (int k = t; k < K; k += 256) {
            const float* er = E + (size_t)k * CDIM;
            float d0 = 0.f, d1 = 0.f, d2 = 0.f, d3 = 0.f;
            for (int c = 0; c < 256; ++c) {
                float ec = er[c];
                d0 = fmaf(zrow[0][c], ec, d0);
                d1 = fmaf(zrow[1][c], ec, d1);
                d2 = fmaf(zrow[2][c], ec, d2);
                d3 = fmaf(zrow[3][c], ec, d3);
            }
            float en = en2k[k];
            float dd[4] = { en - 2.f * d0, en - 2.f * d1, en - 2.f * d2, en - 2.f * d3 };
#pragma unroll
            for (int e = 0; e < 4; ++e)
                if (dd[e] < bv[e]) { bv[e] = dd[e]; bk[e] = k; }
        }
#pragma unroll
        for (int e = 0; e < 4; ++e) { rv[e][t] = bv[e]; rk[e][t] = bk[e]; }
        __syncthreads();
        for (int s2 = 128; s2 > 0; s2 >>= 1) {
            if (t < s2) {
#pragma unroll
                for (int e = 0; e < 4; ++e) {
                    float ov = rv[e][t + s2]; int ok = rk[e][t + s2];
                    if (ov < rv[e][t] || (ov == rv[e][t] && ok < rk[e][t])) {
                        rv[e][t] = ov; rk[e][t] = ok;
                    }
                }
            }
            __syncthreads();
        }
        if (t == 0) {
            for (int e = 0; e < ne; ++e) {
                int n = ns[e]; int nk = rk[e][0];
                int old = idx_i[n];
                if (old != nk) {
                    atomicSub(&cnt[old], 1);
                    atomicAdd(&cnt[nk], 1);
                    idx_i[n] = nk;
                    idx_f[n] = (float)nk;
                }
            }
        }
    }
}

// ---------------------------------------------------------------------------
// Per-codebook: prefix-sum of counts (sort bases) + EMA balance scale.
__global__ void scanbal_kernel(const float* __restrict__ cs_in, const float* __restrict__ cy_in,
                               const int* __restrict__ cnt_s, const int* __restrict__ cnt_y,
                               int* __restrict__ base_s, int* __restrict__ base_y,
                               int* __restrict__ cur_s, int* __restrict__ cur_y,
                               float* __restrict__ scale_s, float* __restrict__ scale_y) {
    __shared__ int   sc[1024];
    __shared__ float sf[1024];
    int K = blockIdx.x ? KY : KS;
    const float* csi = blockIdx.x ? cy_in : cs_in;
    const int*   cnt = blockIdx.x ? cnt_y : cnt_s;
    int* base = blockIdx.x ? base_y : base_s;
    int* cur  = blockIdx.x ? cur_y  : cur_s;
    float* scale = blockIdx.x ? scale_y : scale_s;
    int t = threadIdx.x;
    int c = (t < K) ? cnt[t] : 0;
    float ncs = (t < K) ? (csi[t] * 0.99f + 0.01f * (float)c) : 0.f;
    sc[t] = c;
    __syncthreads();
    for (int off = 1; off < 1024; off <<= 1) {
        int v = sc[t] + ((t >= off) ? sc[t - off] : 0);
        __syncthreads();
        sc[t] = v;
        __syncthreads();
    }
    int incl = sc[t];
    sf[t] = ncs;
    __syncthreads();
    for (int s2 = 512; s2 > 0; s2 >>= 1) {
        if (t < s2) sf[t] += sf[t + s2];
        __syncthreads();
    }
    float nsum = sf[0];
    if (t < K) {
        base[t] = incl - c;
        cur[t]  = incl - c;
        float bal = (ncs + 1e-5f) / (nsum + (float)K * 1e-5f) * nsum;
        scale[t] = 1.0f / bal;
    }
}

__global__ void scatter_kernel(const int* __restrict__ si, const int* __restrict__ yi,
                               int* __restrict__ cur_s, int* __restrict__ cur_y,
                               int* __restrict__ perm_s, int* __restrict__ perm_y,
                               int* __restrict__ ksort_s, int* __restrict__ ksort_y) {
    int i = blockIdx.x * 256 + threadIdx.x;
    if (i < NROWS) {
        int k = si[i]; int p = atomicAdd(&cur_s[k], 1);
        perm_s[p] = i; ksort_s[p] = k;
    } else {
        int n = i - NROWS; int k = yi[n]; int p = atomicAdd(&cur_y[k], 1);
        perm_y[p] = n; ksort_y[p] = k;
    }
}

// ---------------------------------------------------------------------------
// Chunked segmented sum over sorted rows: block = 32 sorted positions,
// thread = channel. Runs flushed with fp32 atomics.
__global__ void dw_kernel(const float* __restrict__ zf,
                          const int* __restrict__ perm_s, const int* __restrict__ ksort_s,
                          const int* __restrict__ perm_y, const int* __restrict__ ksort_y,
                          float* __restrict__ dw_s, float* __restrict__ dw_y) {
    __shared__ int keys[33];
    __shared__ int rows[32];
    const int t = threadIdx.x;
    int blk = blockIdx.x;
    const int* perm; const int* ks; float* dw; int p0;
    if (blk < NROWS / 32) { perm = perm_s; ks = ksort_s; dw = dw_s; p0 = blk * 32; }
    else                  { perm = perm_y; ks = ksort_y; dw = dw_y; p0 = (blk - NROWS / 32) * 32; }
    if (t < 32) { keys[t] = ks[p0 + t]; rows[t] = perm[p0 + t]; }
    if (t == 32) keys[32] = -1;
    __syncthreads();
    float acc = 0.f;
#pragma unroll 8
    for (int j = 0; j < 32; ++j) {
        acc += zf[(size_t)rows[j] * 256 + t];
        if (keys[j + 1] != keys[j]) {
            atomicAdd(&dw[(size_t)keys[j] * 256 + t], acc);
            acc = 0.f;
        }
    }
}

__global__ void embnew_kernel(const float* __restrict__ avg_s, const float* __restrict__ avg_y,
                              const float* __restrict__ dw_s, const float* __restrict__ dw_y,
                              const float* __restrict__ scale_s, const float* __restrict__ scale_y,
                              float* __restrict__ emb_s, float* __restrict__ emb_y) {
    int id = blockIdx.x, t = threadIdx.x;
    if (id < KS) { int i = id * 256 + t; emb_s[i] = (avg_s[i] * 0.99f + 0.01f * dw_s[i]) * scale_s[id]; }
    else { int kk = id - KS; int i = kk * 256 + t; emb_y[i] = (avg_y[i] * 0.99f + 0.01f * dw_y[i]) * scale_y[kk]; }
}

// ---------------------------------------------------------------------------
__global__ void gather_kernel(const float* __restrict__ Se, const float* __restrict__ Ye,
                              const int* __restrict__ sidx, const int* __restrict__ yidx,
                              float* __restrict__ zq, float* __restrict__ disacc) {
    __shared__ float qb[256 * 17];
    __shared__ int   si[16], yi[16];
    __shared__ float red[256];
    const int g  = blockIdx.x;        // b*256 + hw
    const int b  = g >> 8;
    const int hw = g & 255;
    const int t  = threadIdx.x;       // channel
    if (t < 16) {
        int n = b * SPB + hw * 16 + t;
        si[t] = sidx[n];
        yi[t] = yidx[n];
    }
    __syncthreads();
    float ns = 0.f, ny = 0.f, dot = 0.f;
#pragma unroll
    for (int d = 0; d < 16; ++d) {
        float s = Se[(size_t)si[d] * CDIM + t];
        float y = Ye[(size_t)yi[d] * CDIM + t];
        ns  = fmaf(s, s, ns);
        ny  = fmaf(y, y, ny);
        dot = fmaf(s, y, dot);
        qb[t * 17 + d] = 0.5f * (s + y);
    }
    float den = fmaxf(sqrtf(ns), 1e-12f) * fmaxf(sqrtf(ny), 1e-12f);
    float val = dot / den;
    red[t] = val * val;
    __syncthreads();
    for (int s = 128; s > 0; s >>= 1) {
        if (t < s) red[t] += red[t + s];
        __syncthreads();
    }
    if (t == 0) atomicAdd(disacc, red[0]);
    float* zg = zq + (size_t)b * CDIM * SPB + hw * 16;
#pragma unroll
    for (int j = 0; j < 16; ++j) {
        int e = j * 256 + t;
        int c = e >> 4, d = e & 15;
        zg[(size_t)c * SPB + d] = qb[c * 17 + d];
    }
}

__global__ void fin_kernel(const float* __restrict__ disacc, float* __restrict__ out_dis) {
    *out_dis = *disacc * (1.0f / 1048576.0f);
}

// ---------------------------------------------------------------------------
extern "C" void kernel_launch(void* const* d_in, const int* in_sizes, int n_in,
                              void* d_out, int out_size, void* d_ws, size_t ws_size,
                              hipStream_t stream) {
    const float* z     = (const float*)d_in[0];
    const float* Es    = (const float*)d_in[1];
    const float* Ey    = (const float*)d_in[2];
    const float* s_cs  = (const float*)d_in[3];
    const float* y_cs  = (const float*)d_in[4];
    const float* s_avg = (const float*)d_in[5];
    const float* y_avg = (const float*)d_in[6];
    float* out = (float*)d_out;
    char*  w   = (char*)d_ws;

    unsigned short* eimg = (unsigned short*)(w + WB_EIMG);
    float* en2    = (float*)(w + WB_EN2);
    int* idxs_i   = (int*)(w + WB_IDXS_I);
    int* idxy_i   = (int*)(w + WB_IDXY_I);
    int* cnt_s    = (int*)(w + WB_CNT_S);
    int* cnt_y    = (int*)(w + WB_CNT_Y);
    int* r_cnt    = (int*)(w + WB_RESCUE_CNT);
    int* rlist_s  = (int*)(w + WB_RLIST_S);
    int* rlist_y  = (int*)(w + WB_RLIST_Y);
    int* base_s   = (int*)(w + WB_BASE_S);
    int* base_y   = (int*)(w + WB_BASE_Y);
    int* cur_s    = (int*)(w + WB_CUR_S);
    int* cur_y    = (int*)(w + WB_CUR_Y);
    float* scale_s = (float*)(w + WB_SCALE_S);
    float* scale_y = (float*)(w + WB_SCALE_Y);
    int* perm_s   = (int*)(w + WB_PERM_S);
    int* perm_y   = (int*)(w + WB_PERM_Y);
    int* ksort_s  = (int*)(w + WB_KSORT_S);
    int* ksort_y  = (int*)(w + WB_KSORT_Y);
    float* dw_s   = (float*)(w + WB_DW_S);
    float* dw_y   = (float*)(w + WB_DW_Y);
    float* emb_s  = (float*)(w + WB_EMB_S);
    float* emb_y  = (float*)(w + WB_EMB_Y);

    float* zf     = out + OFF_OUT_ZQ;        // zq region reused as fp32 z^T scratch
    float* sidx_f = out + OFF_OUT_SIDX;
    float* yidx_f = out + OFF_OUT_YIDX;

    hipMemsetAsync(w, 0, WB_ZERO_BYTES, stream);

    prep_e<<<KTOT, 64, 0, stream>>>(Es, Ey, eimg, en2);
    prep_z<<<NROWS / 32, 256, 0, stream>>>(z, zf);

    assign_kernel<<<NROWS / 64, 128, 0, stream>>>(z, eimg, en2, sidx_f, yidx_f,
                                                  idxs_i, idxy_i, cnt_s, cnt_y,
                                                  r_cnt, rlist_s, rlist_y);

    rescue_kernel<<<256, 256, 0, stream>>>(z, Es, en2, KS, r_cnt, rlist_s,
                                           sidx_f, idxs_i, cnt_s);
    rescue_kernel<<<256, 256, 0, stream>>>(z, Ey, en2 + KS, KY, r_cnt + 1, rlist_y,
                                           yidx_f, idxy_i, cnt_y);

    scanbal_kernel<<<2, 1024, 0, stream>>>(s_cs, y_cs, cnt_s, cnt_y, base_s, base_y,
                                           cur_s, cur_y, scale_s, scale_y);
    scatter_kernel<<<2 * NROWS / 256, 256, 0, stream>>>(idxs_i, idxy_i, cur_s, cur_y,
                                                        perm_s, perm_y, ksort_s, ksort_y);
    dw_kernel<<<2 * NROWS / 32, 256, 0, stream>>>(zf, perm_s, ksort_s, perm_y, ksort_y, dw_s, dw_y);
    embnew_kernel<<<KTOT, 256, 0, stream>>>(s_avg, y_avg, dw_s, dw_y, scale_s, scale_y, emb_s, emb_y);
    gather_kernel<<<4096, 256, 0, stream>>>(emb_s, emb_y, idxs_i, idxy_i,
                                            out + OFF_OUT_ZQ, (float*)(w + WB_DISACC));
    fin_kernel<<<1, 1, 0, stream>>>((float*)(w + WB_DISACC), out + OFF_OUT_DIS);
}

// Round 5
// 338.977 us; speedup vs baseline: 16.8758x; 1.4446x over previous
//
#include <hip/hip_runtime.h>
#include <float.h>

// Problem constants
#define NROWS 65536      // B*H*W*D
#define CDIM  256
#define KS    1024
#define KY    512
#define KTOT  1536
#define SPB   4096       // H*W*D per batch

// ---- workspace byte offsets ----
#define WB_CNT_S       0         // 1024 int
#define WB_CNT_Y       4096      // 512 int
#define WB_RESCUE_CNT  6144      // 2 int
#define WB_DISACC      6152      // 1 float
#define WB_DW_S        6400      // 1024*256 f32
#define WB_DW_Y        1054976   // 512*256 f32
#define WB_ZERO_BYTES  1579264   // memset [0, here): cnt, rescue_cnt, disacc, dw
#define WB_EIMG        1579264   // 48 chunks * 16384 B (fp16 image)
#define WB_EN2         2365696   // 1536 f32
#define WB_IDXS_I      2371840   // 65536 int
#define WB_IDXY_I      2633984   // 65536 int
#define WB_RLIST_S     2896128   // 65536 int
#define WB_RLIST_Y     3158272   // 65536 int
#define WB_BASE_S      3420416   // 1024 int
#define WB_BASE_Y      3424512   // 512 int
#define WB_CUR_S       3426560   // 1024 int
#define WB_CUR_Y       3430656   // 512 int
#define WB_SCALE_S     3432704   // 1024 f32
#define WB_SCALE_Y     3436800   // 512 f32
#define WB_PERM_S      3438848   // 65536 int
#define WB_PERM_Y      3700992   // 65536 int
#define WB_KSORT_S     3963136   // 65536 int
#define WB_KSORT_Y     4225280   // 65536 int
#define WB_EMB_S       4487424   // 1024*256 f32
#define WB_EMB_Y       5536000   // 512*256 f32

// ---- output float offsets ----
#define OFF_OUT_ZQ   0
#define OFF_OUT_DIS  16777216
#define OFF_OUT_SIDX 16777217
#define OFF_OUT_YIDX 16842753

typedef __attribute__((ext_vector_type(8)))  _Float16 f16x8;
typedef __attribute__((ext_vector_type(16))) float    f32x16;

__device__ __forceinline__ unsigned int umn(unsigned int a, unsigned int b) { return a < b ? a : b; }
__device__ __forceinline__ unsigned int umx(unsigned int a, unsigned int b) { return a > b ? a : b; }

// ---------------------------------------------------------------------------
// Codebook prep: combined (structure ++ style) -> fp16 fragment-linear image
// (chunk = 32 codes = 16KB) + exact fp32 |e|^2. One 64-lane wave per code.
__global__ void prep_e(const float* __restrict__ Es, const float* __restrict__ Ey,
                       unsigned short* __restrict__ eimg, float* __restrict__ en2) {
    int k = blockIdx.x;            // 0..1535 global code
    int lane = threadIdx.x;        // 64
    const float* E = (k < KS) ? (Es + (size_t)k * CDIM) : (Ey + (size_t)(k - KS) * CDIM);
    float4 v = *(const float4*)(E + lane * 4);
    float nrm = v.x * v.x + v.y * v.y + v.z * v.z + v.w * v.w;
#pragma unroll
    for (int off = 32; off > 0; off >>= 1) nrm += __shfl_down(nrm, off);
    if (lane == 0) en2[k] = nrm;

    unsigned short q0 = __builtin_bit_cast(unsigned short, (_Float16)v.x);
    unsigned short q1 = __builtin_bit_cast(unsigned short, (_Float16)v.y);
    unsigned short q2 = __builtin_bit_cast(unsigned short, (_Float16)v.z);
    unsigned short q3 = __builtin_bit_cast(unsigned short, (_Float16)v.w);
    uint2 hp = make_uint2((unsigned)q0 | ((unsigned)q1 << 16),
                          (unsigned)q2 | ((unsigned)q3 << 16));

    int t = k >> 5, kin = k & 31;
    int cc = lane >> 2, g = (lane >> 1) & 1, j0 = (lane & 1) * 4;
    // chunk t: 16 cc-blocks of 1024B; lane slot = kin + 32*g, 8 fp16 each
    size_t base = (size_t)t * 8192 + (size_t)(cc * 512) + (size_t)((kin + 32 * g) * 8 + j0);
    *(uint2*)(eimg + base) = hp;
}

// ---------------------------------------------------------------------------
// Transpose z -> zf[n][c] fp32 (written into d_out zq region as scratch).
__global__ void prep_z(const float* __restrict__ z, float* __restrict__ zf) {
    __shared__ float Zs[32][257];
    int blk = blockIdx.x;          // 2048
    int n0 = blk * 32, b = n0 >> 12, s0 = n0 & 4095;
    int t = threadIdx.x;
    const float* zb = z + (size_t)b * CDIM * SPB + s0;
#pragma unroll
    for (int i = 0; i < 32; ++i) {
        int l = i * 256 + t;       // c*32 + s
        int c = l >> 5, s = l & 31;
        Zs[s][c] = zb[(size_t)c * SPB + s];
    }
    __syncthreads();
#pragma unroll
    for (int j = 0; j < 8; ++j) {
        int gid = j * 256 + t;     // nl*64 + fg
        int nl = gid >> 6, fg = gid & 63;
        float4 v = *(const float4*)(&Zs[nl][fg * 4]);
        *(float4*)(&zf[(size_t)(n0 + nl) * 256 + fg * 4]) = v;
    }
}

// ---------------------------------------------------------------------------
// Stage one 16KB chunk into an LDS buffer via global_load_lds (2 waves).
__device__ __forceinline__ void stage_chunk(const unsigned short* __restrict__ eimg,
                                            int t, unsigned short* lsbase,
                                            int wave, int lane) {
    const char* gs = (const char*)eimg + (size_t)t * 16384 + wave * 8192 + lane * 16;
    char* ls = (char*)lsbase + wave * 8192;
#pragma unroll
    for (int i = 0; i < 8; ++i)
        __builtin_amdgcn_global_load_lds(
            (const __attribute__((address_space(1))) void*)(gs + i * 1024),
            (__attribute__((address_space(3))) void*)(ls + i * 1024), 16, 0, 0);
}

// ---------------------------------------------------------------------------
// MFMA assign: 128 threads = 2 waves x 32 rows; fp16 distance estimate over
// both codebooks; tag-packed argmin; double-buffered staging (counted vmcnt);
// fused count histogram; flags near-ties with their top-2 candidate.
__launch_bounds__(128, 2)
__global__ void assign_kernel(const float* __restrict__ z, const unsigned short* __restrict__ eimg,
                              const float* __restrict__ en2,
                              float* __restrict__ sidx_f, float* __restrict__ yidx_f,
                              int* __restrict__ sidx_i, int* __restrict__ yidx_i,
                              int* __restrict__ cnt_s, int* __restrict__ cnt_y,
                              int* __restrict__ rescue_cnt,
                              int* __restrict__ rlist_s, int* __restrict__ rlist_y) {
    __shared__ unsigned short sh[2][8192];    // 2 x 16KB chunk images
    const int tid = threadIdx.x, wave = tid >> 6, lane = tid & 63;
    const int row32 = lane & 31;
    const int n0 = blockIdx.x * 64;
    const int b = n0 >> 12;
    const int myrow_s = (n0 & 4095) + wave * 32 + row32;
    const float* zb = z + (size_t)b * CDIM * SPB;
    const int g8 = (lane >> 5) * 8;

    // prologue: stage chunk 0 into buf 0 (overlaps A-frag build)
    stage_chunk(eimg, 0, &sh[0][0], wave, lane);

    // A fragments: 16 c-chunks, fp16
    f16x8 Ah[16];
#pragma unroll
    for (int cc = 0; cc < 16; ++cc) {
        f16x8 a;
#pragma unroll
        for (int j = 0; j < 8; ++j)
            a[j] = (_Float16)zb[(size_t)(cc * 16 + g8 + j) * SPB + myrow_s];
        Ah[cc] = a;
    }

    unsigned int m1[16], m2[16];
#pragma unroll
    for (int i = 0; i < 16; ++i) { m1[i] = 0xFFFFFFFFu; m2[i] = 0xFFFFFFFFu; }

    for (int t = 0; t < 48; ++t) {
        unsigned short* cur = &sh[t & 1][0];
        if (t + 1 < 48) {
            stage_chunk(eimg, t + 1, &sh[(t + 1) & 1][0], wave, lane);
            asm volatile("s_waitcnt vmcnt(8)" ::: "memory");   // chunk t loads done
        } else {
            asm volatile("s_waitcnt vmcnt(0)" ::: "memory");
        }
        __builtin_amdgcn_s_barrier();
        asm volatile("" ::: "memory");

        const int kglob = t * 32 + row32;
        const float en0 = en2[kglob] + 512.0f;   // pin exponent, keep positive
        f32x16 acc = {};
        const char* shb = (const char*)cur + lane * 16;
#pragma unroll
        for (int cc = 0; cc < 16; ++cc) {
            f16x8 bh = *(const f16x8*)(shb + cc * 1024);
            acc = __builtin_amdgcn_mfma_f32_32x32x16_f16(Ah[cc], bh, acc, 0, 0, 0);
        }
        const unsigned int tag = (unsigned int)kglob;   // 11 bits
#pragma unroll
        for (int i = 0; i < 16; ++i) {
            float d = fmaf(-2.f, acc[i], en0);
            unsigned int du = (__float_as_uint(d) & 0xFFFFF800u) | tag;
            m2[i] = umn(m2[i], umx(m1[i], du));
            m1[i] = umn(m1[i], du);
        }
        asm volatile("s_waitcnt lgkmcnt(0)" ::: "memory");
        __builtin_amdgcn_s_barrier();
        asm volatile("" ::: "memory");

        if (t == 31 || t == 47) {
            const int book = (t == 47);
            float* fo = book ? yidx_f : sidx_f;
            int*   io = book ? yidx_i : sidx_i;
            int*   cb = book ? cnt_y : cnt_s;
            int*   rl = book ? rlist_y : rlist_s;
#pragma unroll
            for (int i = 0; i < 16; ++i) {
                unsigned int v1 = m1[i], v2 = m2[i];
#pragma unroll
                for (int m = 16; m >= 1; m >>= 1) {
                    unsigned int o1 = (unsigned int)__shfl_xor((int)v1, m);
                    unsigned int o2 = (unsigned int)__shfl_xor((int)v2, m);
                    v2 = umn(umn(v2, o2), umx(v1, o1));
                    v1 = umn(v1, o1);
                }
                if (row32 == 0) {
                    int kw  = (int)(v1 & 0x7FFu) - (book ? KS : 0);
                    int k2w = (int)(v2 & 0x7FFu) - (book ? KS : 0);
                    int r = (i & 3) + 8 * (i >> 2) + 4 * (lane >> 5);
                    int n = n0 + wave * 32 + r;
                    fo[n] = (float)kw;
                    io[n] = kw;
                    atomicAdd(&cb[kw], 1);
                    if ((v1 >> 11) + 4 > (v2 >> 11)) {   // masked margin <= 3 units
                        int p = atomicAdd(&rescue_cnt[book], 1);
                        if (p < 65536) rl[p] = n | (k2w << 16);
                    }
                }
            }
            if (t == 31) {
#pragma unroll
                for (int i = 0; i < 16; ++i) { m1[i] = 0xFFFFFFFFu; m2[i] = 0xFFFFFFFFu; }
            }
        }
    }
}

// ---------------------------------------------------------------------------
// Exact-fp32 top-2 re-rank for near-tie rows: one wave per flagged row,
// compares only {k1 (current pick), k2 (runner-up)} using contiguous zf rows.
__global__ void rescue2_kernel(const float* __restrict__ zf, const float* __restrict__ E,
                               const float* __restrict__ en2k,
                               const int* __restrict__ rcnt, const int* __restrict__ rlist,
                               float* __restrict__ idx_f, int* __restrict__ idx_i,
                               int* __restrict__ cnt) {
    int ce = *rcnt; if (ce > 65536) ce = 65536;
    const int lane = threadIdx.x & 63;
    const int nw = (gridDim.x * blockDim.x) >> 6;
    for (int e = (int)((blockIdx.x * blockDim.x + threadIdx.x) >> 6); e < ce; e += nw) {
        unsigned int ent = (unsigned int)rlist[e];
        int n  = (int)(ent & 0xFFFFu);
        int k2 = (int)(ent >> 16);
        int k1 = idx_i[n];
        float4 zv = *(const float4*)(zf + (size_t)n * 256 + lane * 4);
        float4 a  = *(const float4*)(E + (size_t)k1 * 256 + lane * 4);
        float4 c  = *(const float4*)(E + (size_t)k2 * 256 + lane * 4);
        float d1 = zv.x * a.x + zv.y * a.y + zv.z * a.z + zv.w * a.w;
        float d2 = zv.x * c.x + zv.y * c.y + zv.z * c.z + zv.w * c.w;
#pragma unroll
        for (int off = 32; off > 0; off >>= 1) {
            d1 += __shfl_down(d1, off);
            d2 += __shfl_down(d2, off);
        }
        if (lane == 0) {
            float dist1 = en2k[k1] - 2.f * d1;
            float dist2 = en2k[k2] - 2.f * d2;
            int nk = (dist2 < dist1 || (dist2 == dist1 && k2 < k1)) ? k2 : k1;
            if (nk != k1) {
                atomicSub(&cnt[k1], 1);
                atomicAdd(&cnt[nk], 1);
                idx_i[n] = nk;
                idx_f[n] = (float)nk;
            }
        }
    }
}

// ---------------------------------------------------------------------------
// Per-codebook: prefix-sum of counts (sort bases) + EMA balance scale.
__global__ void scanbal_kernel(const float* __restrict__ cs_in, const float* __restrict__ cy_in,
                               const int* __restrict__ cnt_s, const int* __restrict__ cnt_y,
                               int* __restrict__ base_s, int* __restrict__ base_y,
                               int* __restrict__ cur_s, int* __restrict__ cur_y,
                               float* __restrict__ scale_s, float* __restrict__ scale_y) {
    __shared__ int   sc[1024];
    __shared__ float sf[1024];
    int K = blockIdx.x ? KY : KS;
    const float* csi = blockIdx.x ? cy_in : cs_in;
    const int*   cnt = blockIdx.x ? cnt_y : cnt_s;
    int* base = blockIdx.x ? base_y : base_s;
    int* cur  = blockIdx.x ? cur_y  : cur_s;
    float* scale = blockIdx.x ? scale_y : scale_s;
    int t = threadIdx.x;
    int c = (t < K) ? cnt[t] : 0;
    float ncs = (t < K) ? (csi[t] * 0.99f + 0.01f * (float)c) : 0.f;
    sc[t] = c;
    __syncthreads();
    for (int off = 1; off < 1024; off <<= 1) {
        int v = sc[t] + ((t >= off) ? sc[t - off] : 0);
        __syncthreads();
        sc[t] = v;
        __syncthreads();
    }
    int incl = sc[t];
    sf[t] = ncs;
    __syncthreads();
    for (int s2 = 512; s2 > 0; s2 >>= 1) {
        if (t < s2) sf[t] += sf[t + s2];
        __syncthreads();
    }
    float nsum = sf[0];
    if (t < K) {
        base[t] = incl - c;
        cur[t]  = incl - c;
        float bal = (ncs + 1e-5f) / (nsum + (float)K * 1e-5f) * nsum;
        scale[t] = 1.0f / bal;
    }
}

__global__ void scatter_kernel(const int* __restrict__ si, const int* __restrict__ yi,
                               int* __restrict__ cur_s, int* __restrict__ cur_y,
                               int* __restrict__ perm_s, int* __restrict__ perm_y,
                               int* __restrict__ ksort_s, int* __restrict__ ksort_y) {
    int i = blockIdx.x * 256 + threadIdx.x;
    if (i < NROWS) {
        int k = si[i]; int p = atomicAdd(&cur_s[k], 1);
        perm_s[p] = i; ksort_s[p] = k;
    } else {
        int n = i - NROWS; int k = yi[n]; int p = atomicAdd(&cur_y[k], 1);
        perm_y[p] = n; ksort_y[p] = k;
    }
}

// ---------------------------------------------------------------------------
// Chunked segmented sum over sorted rows: block = 32 sorted positions,
// thread = channel. Runs flushed with fp32 atomics.
__global__ void dw_kernel(const float* __restrict__ zf,
                          const int* __restrict__ perm_s, const int* __restrict__ ksort_s,
                          const int* __restrict__ perm_y, const int* __restrict__ ksort_y,
                          float* __restrict__ dw_s, float* __restrict__ dw_y) {
    __shared__ int keys[33];
    __shared__ int rows[32];
    const int t = threadIdx.x;
    int blk = blockIdx.x;
    const int* perm; const int* ks; float* dw; int p0;
    if (blk < NROWS / 32) { perm = perm_s; ks = ksort_s; dw = dw_s; p0 = blk * 32; }
    else                  { perm = perm_y; ks = ksort_y; dw = dw_y; p0 = (blk - NROWS / 32) * 32; }
    if (t < 32) { keys[t] = ks[p0 + t]; rows[t] = perm[p0 + t]; }
    if (t == 32) keys[32] = -1;
    __syncthreads();
    float acc = 0.f;
#pragma unroll 8
    for (int j = 0; j < 32; ++j) {
        acc += zf[(size_t)rows[j] * 256 + t];
        if (keys[j + 1] != keys[j]) {
            atomicAdd(&dw[(size_t)keys[j] * 256 + t], acc);
            acc = 0.f;
        }
    }
}

__global__ void embnew_kernel(const float* __restrict__ avg_s, const float* __restrict__ avg_y,
                              const float* __restrict__ dw_s, const float* __restrict__ dw_y,
                              const float* __restrict__ scale_s, const float* __restrict__ scale_y,
                              float* __restrict__ emb_s, float* __restrict__ emb_y) {
    int id = blockIdx.x, t = threadIdx.x;
    if (id < KS) { int i = id * 256 + t; emb_s[i] = (avg_s[i] * 0.99f + 0.01f * dw_s[i]) * scale_s[id]; }
    else { int kk = id - KS; int i = kk * 256 + t; emb_y[i] = (avg_y[i] * 0.99f + 0.01f * dw_y[i]) * scale_y[kk]; }
}

// ---------------------------------------------------------------------------
__global__ void gather_kernel(const float* __restrict__ Se, const float* __restrict__ Ye,
                              const int* __restrict__ sidx, const int* __restrict__ yidx,
                              float* __restrict__ zq, float* __restrict__ disacc) {
    __shared__ float qb[256 * 17];
    __shared__ int   si[16], yi[16];
    __shared__ float red[256];
    const int g  = blockIdx.x;        // b*256 + hw
    const int b  = g >> 8;
    const int hw = g & 255;
    const int t  = threadIdx.x;       // channel
    if (t < 16) {
        int n = b * SPB + hw * 16 + t;
        si[t] = sidx[n];
        yi[t] = yidx[n];
    }
    __syncthreads();
    float ns = 0.f, ny = 0.f, dot = 0.f;
#pragma unroll
    for (int d = 0; d < 16; ++d) {
        float s = Se[(size_t)si[d] * CDIM + t];
        float y = Ye[(size_t)yi[d] * CDIM + t];
        ns  = fmaf(s, s, ns);
        ny  = fmaf(y, y, ny);
        dot = fmaf(s, y, dot);
        qb[t * 17 + d] = 0.5f * (s + y);
    }
    float den = fmaxf(sqrtf(ns), 1e-12f) * fmaxf(sqrtf(ny), 1e-12f);
    float val = dot / den;
    red[t] = val * val;
    __syncthreads();
    for (int s = 128; s > 0; s >>= 1) {
        if (t < s) red[t] += red[t + s];
        __syncthreads();
    }
    if (t == 0) atomicAdd(disacc, red[0]);
    float* zg = zq + (size_t)b * CDIM * SPB + hw * 16;
#pragma unroll
    for (int j = 0; j < 16; ++j) {
        int e = j * 256 + t;
        int c = e >> 4, d = e & 15;
        zg[(size_t)c * SPB + d] = qb[c * 17 + d];
    }
}

__global__ void fin_kernel(const float* __restrict__ disacc, float* __restrict__ out_dis) {
    *out_dis = *disacc * (1.0f / 1048576.0f);
}

// ---------------------------------------------------------------------------
extern "C" void kernel_launch(void* const* d_in, const int* in_sizes, int n_in,
                              void* d_out, int out_size, void* d_ws, size_t ws_size,
                              hipStream_t stream) {
    const float* z     = (const float*)d_in[0];
    const float* Es    = (const float*)d_in[1];
    const float* Ey    = (const float*)d_in[2];
    const float* s_cs  = (const float*)d_in[3];
    const float* y_cs  = (const float*)d_in[4];
    const float* s_avg = (const float*)d_in[5];
    const float* y_avg = (const float*)d_in[6];
    float* out = (float*)d_out;
    char*  w   = (char*)d_ws;

    unsigned short* eimg = (unsigned short*)(w + WB_EIMG);
    float* en2    = (float*)(w + WB_EN2);
    int* idxs_i   = (int*)(w + WB_IDXS_I);
    int* idxy_i   = (int*)(w + WB_IDXY_I);
    int* cnt_s    = (int*)(w + WB_CNT_S);
    int* cnt_y    = (int*)(w + WB_CNT_Y);
    int* r_cnt    = (int*)(w + WB_RESCUE_CNT);
    int* rlist_s  = (int*)(w + WB_RLIST_S);
    int* rlist_y  = (int*)(w + WB_RLIST_Y);
    int* base_s   = (int*)(w + WB_BASE_S);
    int* base_y   = (int*)(w + WB_BASE_Y);
    int* cur_s    = (int*)(w + WB_CUR_S);
    int* cur_y    = (int*)(w + WB_CUR_Y);
    float* scale_s = (float*)(w + WB_SCALE_S);
    float* scale_y = (float*)(w + WB_SCALE_Y);
    int* perm_s   = (int*)(w + WB_PERM_S);
    int* perm_y   = (int*)(w + WB_PERM_Y);
    int* ksort_s  = (int*)(w + WB_KSORT_S);
    int* ksort_y  = (int*)(w + WB_KSORT_Y);
    float* dw_s   = (float*)(w + WB_DW_S);
    float* dw_y   = (float*)(w + WB_DW_Y);
    float* emb_s  = (float*)(w + WB_EMB_S);
    float* emb_y  = (float*)(w + WB_EMB_Y);

    float* zf     = out + OFF_OUT_ZQ;        // zq region reused as fp32 z^T scratch
    float* sidx_f = out + OFF_OUT_SIDX;
    float* yidx_f = out + OFF_OUT_YIDX;

    hipMemsetAsync(w, 0, WB_ZERO_BYTES, stream);

    prep_e<<<KTOT, 64, 0, stream>>>(Es, Ey, eimg, en2);
    prep_z<<<NROWS / 32, 256, 0, stream>>>(z, zf);

    assign_kernel<<<NROWS / 64, 128, 0, stream>>>(z, eimg, en2, sidx_f, yidx_f,
                                                  idxs_i, idxy_i, cnt_s, cnt_y,
                                                  r_cnt, rlist_s, rlist_y);

    rescue2_kernel<<<512, 256, 0, stream>>>(zf, Es, en2, r_cnt, rlist_s,
                                            sidx_f, idxs_i, cnt_s);
    rescue2_kernel<<<512, 256, 0, stream>>>(zf, Ey, en2 + KS, r_cnt + 1, rlist_y,
                                            yidx_f, idxy_i, cnt_y);

    scanbal_kernel<<<2, 1024, 0, stream>>>(s_cs, y_cs, cnt_s, cnt_y, base_s, base_y,
                                           cur_s, cur_y, scale_s, scale_y);
    scatter_kernel<<<2 * NROWS / 256, 256, 0, stream>>>(idxs_i, idxy_i, cur_s, cur_y,
                                                        perm_s, perm_y, ksort_s, ksort_y);
    dw_kernel<<<2 * NROWS / 32, 256, 0, stream>>>(zf, perm_s, ksort_s, perm_y, ksort_y, dw_s, dw_y);
    embnew_kernel<<<KTOT, 256, 0, stream>>>(s_avg, y_avg, dw_s, dw_y, scale_s, scale_y, emb_s, emb_y);
    gather_kernel<<<4096, 256, 0, stream>>>(emb_s, emb_y, idxs_i, idxy_i,
                                            out + OFF_OUT_ZQ, (float*)(w + WB_DISACC));
    fin_kernel<<<1, 1, 0, stream>>>((float*)(w + WB_DISACC), out + OFF_OUT_DIS);
}

// Round 6
// 322.187 us; speedup vs baseline: 17.7553x; 1.0521x over previous
//
#include <hip/hip_runtime.h>
#include <float.h>

// Problem constants
#define NROWS 65536      // B*H*W*D
#define CDIM  256
#define KS    1024
#define KY    512
#define KTOT  1536
#define SPB   4096       // H*W*D per batch

// ---- workspace byte offsets ----
#define WB_CNT_S       0         // 1024 int
#define WB_CNT_Y       4096      // 512 int
#define WB_RESCUE_CNT  6144      // 2 int
#define WB_DISACC      6152      // 1 float
#define WB_DW_S        6400      // 1024*256 f32
#define WB_DW_Y        1054976   // 512*256 f32
#define WB_ZERO_BYTES  1579264   // memset [0, here): cnt, rescue_cnt, disacc, dw
#define WB_EIMG        1579264   // 96 chunks * 8192 B (fp16 image, 16 codes/chunk)
#define WB_EN2         2365696   // 1536 f32
#define WB_IDXS_I      2371840   // 65536 int
#define WB_IDXY_I      2633984   // 65536 int
#define WB_RLIST_S     2896128   // 65536 int
#define WB_RLIST_Y     3158272   // 65536 int
#define WB_BASE_S      3420416   // 1024 int
#define WB_BASE_Y      3424512   // 512 int
#define WB_CUR_S       3426560   // 1024 int
#define WB_CUR_Y       3430656   // 512 int
#define WB_SCALE_S     3432704   // 1024 f32
#define WB_SCALE_Y     3436800   // 512 f32
#define WB_PERM_S      3438848   // 65536 int
#define WB_PERM_Y      3700992   // 65536 int
#define WB_KSORT_S     3963136   // 65536 int
#define WB_KSORT_Y     4225280   // 65536 int
#define WB_EMB_S       4487424   // 1024*256 f32
#define WB_EMB_Y       5536000   // 512*256 f32

// ---- output float offsets ----
#define OFF_OUT_ZQ   0
#define OFF_OUT_DIS  16777216
#define OFF_OUT_SIDX 16777217
#define OFF_OUT_YIDX 16842753

typedef __attribute__((ext_vector_type(8)))  _Float16 f16x8;
typedef __attribute__((ext_vector_type(4)))  float    f32x4;

__device__ __forceinline__ unsigned int umn(unsigned int a, unsigned int b) { return a < b ? a : b; }
__device__ __forceinline__ unsigned int umx(unsigned int a, unsigned int b) { return a > b ? a : b; }

// ---------------------------------------------------------------------------
// Codebook prep -> fp16 fragment image for 16x16x32 MFMA B-operand.
// Chunk = 16 codes = 8KB. Within chunk: kc(0..7) blocks of 1KB; within block
// lane l reads 16B at l*16 = code (l&15), channels kc*32 + (l>>4)*8 + j.
__global__ void prep_e(const float* __restrict__ Es, const float* __restrict__ Ey,
                       unsigned short* __restrict__ eimg, float* __restrict__ en2) {
    int k = blockIdx.x;            // 0..1535 global code
    int lane = threadIdx.x;        // 64
    const float* E = (k < KS) ? (Es + (size_t)k * CDIM) : (Ey + (size_t)(k - KS) * CDIM);
    float4 v = *(const float4*)(E + lane * 4);
    float nrm = v.x * v.x + v.y * v.y + v.z * v.z + v.w * v.w;
#pragma unroll
    for (int off = 32; off > 0; off >>= 1) nrm += __shfl_down(nrm, off);
    if (lane == 0) en2[k] = nrm;

    unsigned short q0 = __builtin_bit_cast(unsigned short, (_Float16)v.x);
    unsigned short q1 = __builtin_bit_cast(unsigned short, (_Float16)v.y);
    unsigned short q2 = __builtin_bit_cast(unsigned short, (_Float16)v.z);
    unsigned short q3 = __builtin_bit_cast(unsigned short, (_Float16)v.w);
    uint2 hp = make_uint2((unsigned)q0 | ((unsigned)q1 << 16),
                          (unsigned)q2 | ((unsigned)q3 << 16));

    int c0 = lane * 4;
    int kc = c0 >> 5, g = (c0 >> 3) & 3, j0 = c0 & 7;   // j0 in {0,4}
    size_t byteoff = (size_t)(k >> 4) * 8192 + (size_t)kc * 1024
                   + (size_t)(g * 16 + (k & 15)) * 16 + (size_t)j0 * 2;
    *(uint2*)((char*)eimg + byteoff) = hp;
}

// ---------------------------------------------------------------------------
// Transpose z -> zf[n][c] fp32 (written into d_out zq region as scratch).
__global__ void prep_z(const float* __restrict__ z, float* __restrict__ zf) {
    __shared__ float Zs[32][257];
    int blk = blockIdx.x;          // 2048
    int n0 = blk * 32, b = n0 >> 12, s0 = n0 & 4095;
    int t = threadIdx.x;
    const float* zb = z + (size_t)b * CDIM * SPB + s0;
#pragma unroll
    for (int i = 0; i < 32; ++i) {
        int l = i * 256 + t;       // c*32 + s
        int c = l >> 5, s = l & 31;
        Zs[s][c] = zb[(size_t)c * SPB + s];
    }
    __syncthreads();
#pragma unroll
    for (int j = 0; j < 8; ++j) {
        int gid = j * 256 + t;     // nl*64 + fg
        int nl = gid >> 6, fg = gid & 63;
        float4 v = *(const float4*)(&Zs[nl][fg * 4]);
        *(float4*)(&zf[(size_t)(n0 + nl) * 256 + fg * 4]) = v;
    }
}

// ---------------------------------------------------------------------------
// Stage one 8KB chunk (16 codes) into LDS; each wave of the pair stages 4KB.
__device__ __forceinline__ void stage4(const unsigned short* __restrict__ eimg,
                                       int chunk, char* lsbase, int wrow, int lane) {
    const char* gs = (const char*)eimg + (size_t)chunk * 8192 + wrow * 4096 + lane * 16;
    char* ls = lsbase + wrow * 4096;
#pragma unroll
    for (int i = 0; i < 4; ++i)
        __builtin_amdgcn_global_load_lds(
            (const __attribute__((address_space(1))) void*)(gs + i * 1024),
            (__attribute__((address_space(3))) void*)(ls + i * 1024), 16, 0, 0);
}

// ---------------------------------------------------------------------------
// MFMA assign, K-split: 256 thr = 4 waves. Pair 0 (waves 0,1) scans codes
// [0,768); pair 1 scans [768,1536). Wave wrow covers rows n0+wrow*32..+31 as
// two 16-row A-sets (16x16x32 MFMA; each staged B-frag feeds 2 MFMAs).
// Book-S top-2 merged across pairs via LDS; book Y is pair-1 only.
__launch_bounds__(256, 3)
__global__ void assign_kernel(const float* __restrict__ zf, const unsigned short* __restrict__ eimg,
                              const float* __restrict__ en2,
                              float* __restrict__ sidx_f, float* __restrict__ yidx_f,
                              int* __restrict__ sidx_i, int* __restrict__ yidx_i,
                              int* __restrict__ cnt_s, int* __restrict__ cnt_y,
                              int* __restrict__ rescue_cnt,
                              int* __restrict__ rlist_s, int* __restrict__ rlist_y) {
    __shared__ char shraw[32768];           // 2 pairs x 2 dbuf x 8KB
    __shared__ unsigned int mv1[64], mv2[64];  // pair-1 book-S partial
    const int tid = threadIdx.x, wave = tid >> 6, lane = tid & 63;
    const int pair = wave >> 1, wrow = wave & 1;
    const int n0 = blockIdx.x * 64;
    char* shp = shraw + pair * 16384;

    // prologue: stage first chunk of this pair
    stage4(eimg, pair * 48, shp, wrow, lane);

    // A fragments from zf: 2 row-groups x 8 k-chunks
    f16x8 A[2][8];
#pragma unroll
    for (int rg = 0; rg < 2; ++rg) {
        const float* zr = zf + (size_t)(n0 + wrow * 32 + rg * 16 + (lane & 15)) * 256
                        + (lane >> 4) * 8;
#pragma unroll
        for (int kc = 0; kc < 8; ++kc) {
            float4 f0 = *(const float4*)(zr + kc * 32);
            float4 f1 = *(const float4*)(zr + kc * 32 + 4);
            f16x8 a;
            a[0] = (_Float16)f0.x; a[1] = (_Float16)f0.y;
            a[2] = (_Float16)f0.z; a[3] = (_Float16)f0.w;
            a[4] = (_Float16)f1.x; a[5] = (_Float16)f1.y;
            a[6] = (_Float16)f1.z; a[7] = (_Float16)f1.w;
            A[rg][kc] = a;
        }
    }

    unsigned int m1a[2][4], m2a[2][4];
#pragma unroll
    for (int rg = 0; rg < 2; ++rg)
#pragma unroll
        for (int q = 0; q < 4; ++q) { m1a[rg][q] = 0xFFFFFFFFu; m2a[rg][q] = 0xFFFFFFFFu; }

    for (int i = 0; i < 48; ++i) {
        const int chunk = pair * 48 + i;
        if (i + 1 < 48) {
            stage4(eimg, chunk + 1, shp + ((i + 1) & 1) * 8192, wrow, lane);
            asm volatile("s_waitcnt vmcnt(4)" ::: "memory");
        } else {
            asm volatile("s_waitcnt vmcnt(0)" ::: "memory");
        }
        __builtin_amdgcn_s_barrier();
        asm volatile("" ::: "memory");

        const char* bb = shp + (i & 1) * 8192 + lane * 16;
        f32x4 acc0 = {}, acc1 = {};
#pragma unroll
        for (int kc = 0; kc < 8; ++kc) {
            f16x8 B = *(const f16x8*)(bb + kc * 1024);
            acc0 = __builtin_amdgcn_mfma_f32_16x16x32_f16(A[0][kc], B, acc0, 0, 0, 0);
            acc1 = __builtin_amdgcn_mfma_f32_16x16x32_f16(A[1][kc], B, acc1, 0, 0, 0);
        }
        const int kcode = chunk * 16 + (lane & 15);
        const float en0 = en2[kcode] + 512.0f;    // pin exponent, keep positive
        const unsigned int tag = (unsigned int)kcode;   // 11 bits
#pragma unroll
        for (int q = 0; q < 4; ++q) {
            float d0 = fmaf(-2.f, acc0[q], en0);
            unsigned int du0 = (__float_as_uint(d0) & 0xFFFFF800u) | tag;
            m2a[0][q] = umn(m2a[0][q], umx(m1a[0][q], du0));
            m1a[0][q] = umn(m1a[0][q], du0);
            float d1 = fmaf(-2.f, acc1[q], en0);
            unsigned int du1 = (__float_as_uint(d1) & 0xFFFFF800u) | tag;
            m2a[1][q] = umn(m2a[1][q], umx(m1a[1][q], du1));
            m1a[1][q] = umn(m1a[1][q], du1);
        }
        asm volatile("s_waitcnt lgkmcnt(0)" ::: "memory");
        __builtin_amdgcn_s_barrier();
        asm volatile("" ::: "memory");

        if (pair == 1 && i == 15) {
            // flush book-S partial (codes 768..1023) to LDS, reset for book Y
#pragma unroll
            for (int rg = 0; rg < 2; ++rg)
#pragma unroll
                for (int q = 0; q < 4; ++q) {
                    unsigned int v1 = m1a[rg][q], v2 = m2a[rg][q];
#pragma unroll
                    for (int m = 8; m >= 1; m >>= 1) {
                        unsigned int o1 = (unsigned int)__shfl_xor((int)v1, m);
                        unsigned int o2 = (unsigned int)__shfl_xor((int)v2, m);
                        v2 = umn(umn(v2, o2), umx(v1, o1));
                        v1 = umn(v1, o1);
                    }
                    if ((lane & 15) == 0) {
                        int r64 = wrow * 32 + rg * 16 + (lane >> 4) * 4 + q;
                        mv1[r64] = v1; mv2[r64] = v2;
                    }
                    m1a[rg][q] = 0xFFFFFFFFu; m2a[rg][q] = 0xFFFFFFFFu;
                }
        }
    }

    if (pair == 0) {
        // merge own S-partial (codes 0..767) with pair 1's (768..1023), output S
#pragma unroll
        for (int rg = 0; rg < 2; ++rg)
#pragma unroll
            for (int q = 0; q < 4; ++q) {
                unsigned int v1 = m1a[rg][q], v2 = m2a[rg][q];
#pragma unroll
                for (int m = 8; m >= 1; m >>= 1) {
                    unsigned int o1 = (unsigned int)__shfl_xor((int)v1, m);
                    unsigned int o2 = (unsigned int)__shfl_xor((int)v2, m);
                    v2 = umn(umn(v2, o2), umx(v1, o1));
                    v1 = umn(v1, o1);
                }
                if ((lane & 15) == 0) {
                    int r64 = wrow * 32 + rg * 16 + (lane >> 4) * 4 + q;
                    unsigned int p1 = mv1[r64], p2 = mv2[r64];
                    unsigned int nv2 = umn(umn(v2, p2), umx(v1, p1));
                    unsigned int nv1 = umn(v1, p1);
                    int kw = (int)(nv1 & 0x7FFu);
                    int n = n0 + r64;
                    sidx_f[n] = (float)kw;
                    sidx_i[n] = kw;
                    atomicAdd(&cnt_s[kw], 1);
                    if ((nv1 >> 11) + 4 > (nv2 >> 11)) {
                        int k2w = (int)(nv2 & 0x7FFu);
                        int p = atomicAdd(&rescue_cnt[0], 1);
                        if (p < 65536) rlist_s[p] = n | (k2w << 16);
                    }
                }
            }
    } else {
        // output book Y (pair 1 exclusive)
#pragma unroll
        for (int rg = 0; rg < 2; ++rg)
#pragma unroll
            for (int q = 0; q < 4; ++q) {
                unsigned int v1 = m1a[rg][q], v2 = m2a[rg][q];
#pragma unroll
                for (int m = 8; m >= 1; m >>= 1) {
                    unsigned int o1 = (unsigned int)__shfl_xor((int)v1, m);
                    unsigned int o2 = (unsigned int)__shfl_xor((int)v2, m);
                    v2 = umn(umn(v2, o2), umx(v1, o1));
                    v1 = umn(v1, o1);
                }
                if ((lane & 15) == 0) {
                    int r64 = wrow * 32 + rg * 16 + (lane >> 4) * 4 + q;
                    int kw = (int)(v1 & 0x7FFu) - KS;
                    int n = n0 + r64;
                    yidx_f[n] = (float)kw;
                    yidx_i[n] = kw;
                    atomicAdd(&cnt_y[kw], 1);
                    if ((v1 >> 11) + 4 > (v2 >> 11)) {
                        int k2w = (int)(v2 & 0x7FFu) - KS;
                        int p = atomicAdd(&rescue_cnt[1], 1);
                        if (p < 65536) rlist_y[p] = n | (k2w << 16);
                    }
                }
            }
    }
}

// ---------------------------------------------------------------------------
// Exact-fp32 top-2 re-rank for near-tie rows (both books in one launch):
// one wave per flagged row, compares only {k1, k2} using contiguous zf rows.
__global__ void rescue2_kernel(const float* __restrict__ zf,
                               const float* __restrict__ Es, const float* __restrict__ Ey,
                               const float* __restrict__ en2, const int* __restrict__ rcnt,
                               const int* __restrict__ rlist_s, const int* __restrict__ rlist_y,
                               float* __restrict__ sidx_f, float* __restrict__ yidx_f,
                               int* __restrict__ sidx_i, int* __restrict__ yidx_i,
                               int* __restrict__ cnt_s, int* __restrict__ cnt_y) {
    int cs = rcnt[0]; if (cs > 65536) cs = 65536;
    int cy = rcnt[1]; if (cy > 65536) cy = 65536;
    int total = cs + cy;
    const int lane = threadIdx.x & 63;
    const int nw = (gridDim.x * blockDim.x) >> 6;
    for (int e = (int)((blockIdx.x * blockDim.x + threadIdx.x) >> 6); e < total; e += nw) {
        int book = (e >= cs);
        unsigned int ent = (unsigned int)(book ? rlist_y[e - cs] : rlist_s[e]);
        int n  = (int)(ent & 0xFFFFu);
        int k2 = (int)(ent >> 16);
        int* idx_i = book ? yidx_i : sidx_i;
        float* idx_f = book ? yidx_f : sidx_f;
        int* cnt = book ? cnt_y : cnt_s;
        const float* E = book ? Ey : Es;
        const float* en2k = book ? (en2 + KS) : en2;
        int k1 = idx_i[n];
        float4 zv = *(const float4*)(zf + (size_t)n * 256 + lane * 4);
        float4 a  = *(const float4*)(E + (size_t)k1 * 256 + lane * 4);
        float4 c  = *(const float4*)(E + (size_t)k2 * 256 + lane * 4);
        float d1 = zv.x * a.x + zv.y * a.y + zv.z * a.z + zv.w * a.w;
        float d2 = zv.x * c.x + zv.y * c.y + zv.z * c.z + zv.w * c.w;
#pragma unroll
        for (int off = 32; off > 0; off >>= 1) {
            d1 += __shfl_down(d1, off);
            d2 += __shfl_down(d2, off);
        }
        if (lane == 0) {
            float dist1 = en2k[k1] - 2.f * d1;
            float dist2 = en2k[k2] - 2.f * d2;
            int nk = (dist2 < dist1 || (dist2 == dist1 && k2 < k1)) ? k2 : k1;
            if (nk != k1) {
                atomicSub(&cnt[k1], 1);
                atomicAdd(&cnt[nk], 1);
                idx_i[n] = nk;
                idx_f[n] = (float)nk;
            }
        }
    }
}

// ---------------------------------------------------------------------------
// Per-codebook: prefix-sum of counts (sort bases) + EMA balance scale.
__global__ void scanbal_kernel(const float* __restrict__ cs_in, const float* __restrict__ cy_in,
                               const int* __restrict__ cnt_s, const int* __restrict__ cnt_y,
                               int* __restrict__ base_s, int* __restrict__ base_y,
                               int* __restrict__ cur_s, int* __restrict__ cur_y,
                               float* __restrict__ scale_s, float* __restrict__ scale_y) {
    __shared__ int   sc[1024];
    __shared__ float sf[1024];
    int K = blockIdx.x ? KY : KS;
    const float* csi = blockIdx.x ? cy_in : cs_in;
    const int*   cnt = blockIdx.x ? cnt_y : cnt_s;
    int* base = blockIdx.x ? base_y : base_s;
    int* cur  = blockIdx.x ? cur_y  : cur_s;
    float* scale = blockIdx.x ? scale_y : scale_s;
    int t = threadIdx.x;
    int c = (t < K) ? cnt[t] : 0;
    float ncs = (t < K) ? (csi[t] * 0.99f + 0.01f * (float)c) : 0.f;
    sc[t] = c;
    __syncthreads();
    for (int off = 1; off < 1024; off <<= 1) {
        int v = sc[t] + ((t >= off) ? sc[t - off] : 0);
        __syncthreads();
        sc[t] = v;
        __syncthreads();
    }
    int incl = sc[t];
    sf[t] = ncs;
    __syncthreads();
    for (int s2 = 512; s2 > 0; s2 >>= 1) {
        if (t < s2) sf[t] += sf[t + s2];
        __syncthreads();
    }
    float nsum = sf[0];
    if (t < K) {
        base[t] = incl - c;
        cur[t]  = incl - c;
        float bal = (ncs + 1e-5f) / (nsum + (float)K * 1e-5f) * nsum;
        scale[t] = 1.0f / bal;
    }
}

__global__ void scatter_kernel(const int* __restrict__ si, const int* __restrict__ yi,
                               int* __restrict__ cur_s, int* __restrict__ cur_y,
                               int* __restrict__ perm_s, int* __restrict__ perm_y,
                               int* __restrict__ ksort_s, int* __restrict__ ksort_y) {
    int i = blockIdx.x * 256 + threadIdx.x;
    if (i < NROWS) {
        int k = si[i]; int p = atomicAdd(&cur_s[k], 1);
        perm_s[p] = i; ksort_s[p] = k;
    } else {
        int n = i - NROWS; int k = yi[n]; int p = atomicAdd(&cur_y[k], 1);
        perm_y[p] = n; ksort_y[p] = k;
    }
}

// ---------------------------------------------------------------------------
// Chunked segmented sum over sorted rows: block = 32 sorted positions,
// thread = channel. Runs flushed with fp32 atomics.
__global__ void dw_kernel(const float* __restrict__ zf,
                          const int* __restrict__ perm_s, const int* __restrict__ ksort_s,
                          const int* __restrict__ perm_y, const int* __restrict__ ksort_y,
                          float* __restrict__ dw_s, float* __restrict__ dw_y) {
    __shared__ int keys[33];
    __shared__ int rows[32];
    const int t = threadIdx.x;
    int blk = blockIdx.x;
    const int* perm; const int* ks; float* dw; int p0;
    if (blk < NROWS / 32) { perm = perm_s; ks = ksort_s; dw = dw_s; p0 = blk * 32; }
    else                  { perm = perm_y; ks = ksort_y; dw = dw_y; p0 = (blk - NROWS / 32) * 32; }
    if (t < 32) { keys[t] = ks[p0 + t]; rows[t] = perm[p0 + t]; }
    if (t == 32) keys[32] = -1;
    __syncthreads();
    float acc = 0.f;
#pragma unroll 8
    for (int j = 0; j < 32; ++j) {
        acc += zf[(size_t)rows[j] * 256 + t];
        if (keys[j + 1] != keys[j]) {
            atomicAdd(&dw[(size_t)keys[j] * 256 + t], acc);
            acc = 0.f;
        }
    }
}

__global__ void embnew_kernel(const float* __restrict__ avg_s, const float* __restrict__ avg_y,
                              const float* __restrict__ dw_s, const float* __restrict__ dw_y,
                              const float* __restrict__ scale_s, const float* __restrict__ scale_y,
                              float* __restrict__ emb_s, float* __restrict__ emb_y) {
    int id = blockIdx.x, t = threadIdx.x;
    if (id < KS) { int i = id * 256 + t; emb_s[i] = (avg_s[i] * 0.99f + 0.01f * dw_s[i]) * scale_s[id]; }
    else { int kk = id - KS; int i = kk * 256 + t; emb_y[i] = (avg_y[i] * 0.99f + 0.01f * dw_y[i]) * scale_y[kk]; }
}

// ---------------------------------------------------------------------------
__global__ void gather_kernel(const float* __restrict__ Se, const float* __restrict__ Ye,
                              const int* __restrict__ sidx, const int* __restrict__ yidx,
                              float* __restrict__ zq, float* __restrict__ disacc) {
    __shared__ float qb[256 * 17];
    __shared__ int   si[16], yi[16];
    __shared__ float red[256];
    const int g  = blockIdx.x;        // b*256 + hw
    const int b  = g >> 8;
    const int hw = g & 255;
    const int t  = threadIdx.x;       // channel
    if (t < 16) {
        int n = b * SPB + hw * 16 + t;
        si[t] = sidx[n];
        yi[t] = yidx[n];
    }
    __syncthreads();
    float ns = 0.f, ny = 0.f, dot = 0.f;
#pragma unroll
    for (int d = 0; d < 16; ++d) {
        float s = Se[(size_t)si[d] * CDIM + t];
        float y = Ye[(size_t)yi[d] * CDIM + t];
        ns  = fmaf(s, s, ns);
        ny  = fmaf(y, y, ny);
        dot = fmaf(s, y, dot);
        qb[t * 17 + d] = 0.5f * (s + y);
    }
    float den = fmaxf(sqrtf(ns), 1e-12f) * fmaxf(sqrtf(ny), 1e-12f);
    float val = dot / den;
    red[t] = val * val;
    __syncthreads();
    for (int s = 128; s > 0; s >>= 1) {
        if (t < s) red[t] += red[t + s];
        __syncthreads();
    }
    if (t == 0) atomicAdd(disacc, red[0]);
    float* zg = zq + (size_t)b * CDIM * SPB + hw * 16;
#pragma unroll
    for (int j = 0; j < 16; ++j) {
        int e = j * 256 + t;
        int c = e >> 4, d = e & 15;
        zg[(size_t)c * SPB + d] = qb[c * 17 + d];
    }
}

__global__ void fin_kernel(const float* __restrict__ disacc, float* __restrict__ out_dis) {
    *out_dis = *disacc * (1.0f / 1048576.0f);
}

// ---------------------------------------------------------------------------
extern "C" void kernel_launch(void* const* d_in, const int* in_sizes, int n_in,
                              void* d_out, int out_size, void* d_ws, size_t ws_size,
                              hipStream_t stream) {
    const float* z     = (const float*)d_in[0];
    const float* Es    = (const float*)d_in[1];
    const float* Ey    = (const float*)d_in[2];
    const float* s_cs  = (const float*)d_in[3];
    const float* y_cs  = (const float*)d_in[4];
    const float* s_avg = (const float*)d_in[5];
    const float* y_avg = (const float*)d_in[6];
    float* out = (float*)d_out;
    char*  w   = (char*)d_ws;

    unsigned short* eimg = (unsigned short*)(w + WB_EIMG);
    float* en2    = (float*)(w + WB_EN2);
    int* idxs_i   = (int*)(w + WB_IDXS_I);
    int* idxy_i   = (int*)(w + WB_IDXY_I);
    int* cnt_s    = (int*)(w + WB_CNT_S);
    int* cnt_y    = (int*)(w + WB_CNT_Y);
    int* r_cnt    = (int*)(w + WB_RESCUE_CNT);
    int* rlist_s  = (int*)(w + WB_RLIST_S);
    int* rlist_y  = (int*)(w + WB_RLIST_Y);
    int* base_s   = (int*)(w + WB_BASE_S);
    int* base_y   = (int*)(w + WB_BASE_Y);
    int* cur_s    = (int*)(w + WB_CUR_S);
    int* cur_y    = (int*)(w + WB_CUR_Y);
    float* scale_s = (float*)(w + WB_SCALE_S);
    float* scale_y = (float*)(w + WB_SCALE_Y);
    int* perm_s   = (int*)(w + WB_PERM_S);
    int* perm_y   = (int*)(w + WB_PERM_Y);
    int* ksort_s  = (int*)(w + WB_KSORT_S);
    int* ksort_y  = (int*)(w + WB_KSORT_Y);
    float* dw_s   = (float*)(w + WB_DW_S);
    float* dw_y   = (float*)(w + WB_DW_Y);
    float* emb_s  = (float*)(w + WB_EMB_S);
    float* emb_y  = (float*)(w + WB_EMB_Y);

    float* zf     = out + OFF_OUT_ZQ;        // zq region reused as fp32 z^T scratch
    float* sidx_f = out + OFF_OUT_SIDX;
    float* yidx_f = out + OFF_OUT_YIDX;

    hipMemsetAsync(w, 0, WB_ZERO_BYTES, stream);

    prep_e<<<KTOT, 64, 0, stream>>>(Es, Ey, eimg, en2);
    prep_z<<<NROWS / 32, 256, 0, stream>>>(z, zf);

    assign_kernel<<<NROWS / 64, 256, 0, stream>>>(zf, eimg, en2, sidx_f, yidx_f,
                                                  idxs_i, idxy_i, cnt_s, cnt_y,
                                                  r_cnt, rlist_s, rlist_y);

    rescue2_kernel<<<512, 256, 0, stream>>>(zf, Es, Ey, en2, r_cnt, rlist_s, rlist_y,
                                            sidx_f, yidx_f, idxs_i, idxy_i, cnt_s, cnt_y);

    scanbal_kernel<<<2, 1024, 0, stream>>>(s_cs, y_cs, cnt_s, cnt_y, base_s, base_y,
                                           cur_s, cur_y, scale_s, scale_y);
    scatter_kernel<<<2 * NROWS / 256, 256, 0, stream>>>(idxs_i, idxy_i, cur_s, cur_y,
                                                        perm_s, perm_y, ksort_s, ksort_y);
    dw_kernel<<<2 * NROWS / 32, 256, 0, stream>>>(zf, perm_s, ksort_s, perm_y, ksort_y, dw_s, dw_y);
    embnew_kernel<<<KTOT, 256, 0, stream>>>(s_avg, y_avg, dw_s, dw_y, scale_s, scale_y, emb_s, emb_y);
    gather_kernel<<<4096, 256, 0, stream>>>(emb_s, emb_y, idxs_i, idxy_i,
                                            out + OFF_OUT_ZQ, (float*)(w + WB_DISACC));
    fin_kernel<<<1, 1, 0, stream>>>((float*)(w + WB_DISACC), out + OFF_OUT_DIS);
}